// Round 5
// baseline (211.378 us; speedup 1.0000x reference)
//
#include <hip/hip_runtime.h>

#define S_LEN 2048
#define D_DIM 1024
#define NHEAD 16
#define DH 64
#define BATCH 2
#define NROWS (BATCH * S_LEN)  // 4096
#define QSCALE 0.18033688011112042f  // 0.125 * log2(e): scores land in log2 domain

typedef __attribute__((ext_vector_type(8))) short short8;
typedef __attribute__((ext_vector_type(4))) float f32x4;
typedef __attribute__((ext_vector_type(2))) unsigned int u32x2;
typedef __attribute__((ext_vector_type(4))) unsigned int u32x4;

static __device__ __forceinline__ unsigned short f2bf(float f) {
    unsigned int u = __builtin_bit_cast(unsigned int, f);
    u += 0x7fffu + ((u >> 16) & 1u);
    return (unsigned short)(u >> 16);
}
static __device__ __forceinline__ float bf2f(unsigned short h) {
    unsigned int u = ((unsigned int)h) << 16;
    return __builtin_bit_cast(float, u);
}

// ---------------- fp32 -> bf16 convert (inputs + weights) + fused padding masks --------
__global__ __launch_bounds__(256) void cvt_all_kernel(
    const float* __restrict__ s0, const float* __restrict__ s1, const float* __restrict__ s2,
    const float* __restrict__ w0, const float* __restrict__ w1, const float* __restrict__ w2,
    unsigned short* __restrict__ d0, unsigned short* __restrict__ d1,
    unsigned short* __restrict__ d2, unsigned short* __restrict__ e0,
    unsigned short* __restrict__ e1, unsigned short* __restrict__ e2,
    float* __restrict__ qm, float* __restrict__ km) {
    const int y = blockIdx.y;
    const int row = blockIdx.x;
    const int t = threadIdx.x;
    const float* src;
    unsigned short* dst;
    size_t i;
    if (row < NROWS) {
        src = y == 0 ? s0 : (y == 1 ? s1 : s2);
        dst = y == 0 ? d0 : (y == 1 ? d1 : d2);
        i = (size_t)row * 256 + t;
    } else {
        src = y == 0 ? w0 : (y == 1 ? w1 : w2);
        dst = y == 0 ? e0 : (y == 1 ? e1 : e2);
        i = (size_t)(row - NROWS) * 256 + t;
    }
    float4 v = ((const float4*)src)[i];
    ushort4 o;
    o.x = f2bf(v.x); o.y = f2bf(v.y); o.z = f2bf(v.z); o.w = f2bf(v.w);
    ((ushort4*)dst)[i] = o;
    if (row < NROWS && y < 2) {
        float s = v.x + v.y + v.z + v.w;
        for (int off = 1; off < 64; off <<= 1) s += __shfl_xor(s, off);
        __shared__ float red[4];
        const int w = t >> 6;
        if ((t & 63) == 0) red[w] = s;
        __syncthreads();
        if (t == 0) {
            float tt = red[0] + red[1] + red[2] + red[3];
            if (y == 0)
                qm[row] = (tt != 0.0f) ? 1.0f : 0.0f;
            else
                km[row] = (tt != 0.0f) ? 0.0f : -4294967295.0f;
        }
    }
}

// ---------------- fused QKV projection: O = relu(A @ W^T + b), bf16 MFMA ----------------
// R4 distance-2 pipeline (3 LDS bufs, counted vmcnt(4), GLDS(kt+2) issued at iter kt).
// R5: z==2 (V) writes output DIRECTLY in (B,H,dh,S) transposed layout (O2 is Vt);
// each lane packs acc[i][j][0..3] (4 consecutive s, one d) into one 8B store.
// Bit-identical values to the old Vb+transpose_v path; kills a whole kernel.
__global__ __launch_bounds__(256) void proj_kernel(
    const unsigned short* __restrict__ A0, const unsigned short* __restrict__ A1,
    const unsigned short* __restrict__ A2, const unsigned short* __restrict__ W0,
    const unsigned short* __restrict__ W1, const unsigned short* __restrict__ W2,
    const float* __restrict__ b0, const float* __restrict__ b1, const float* __restrict__ b2,
    unsigned short* __restrict__ O0, unsigned short* __restrict__ O1,
    unsigned short* __restrict__ O2) {
    const int u = blockIdx.x;
    const int n = u / 96;
    const int rem = u % 96;
    const int m = rem / 3;
    const int z = rem % 3;
    const unsigned short* A;
    const unsigned short* W;
    const float* bias;
    unsigned short* O;
    if (z == 0) { A = A0; W = W0; bias = b0; O = O0; }
    else if (z == 1) { A = A1; W = W1; bias = b1; O = O1; }
    else { A = A2; W = W2; bias = b2; O = O2; }

    __shared__ __align__(16) unsigned short Asm[3][128 * 32];
    __shared__ __align__(16) unsigned short Bsm[3][128 * 32];

    const int t = threadIdx.x;
    const int w = t >> 6, l = t & 63;
    const int quad = l >> 4, lr = l & 15;
    const int wm = w >> 1, wn = w & 1;
    const int m0 = m * 128, n0 = n * 128;

    f32x4 zero = {0.f, 0.f, 0.f, 0.f};
    f32x4 acc[4][4];
#pragma unroll
    for (int i = 0; i < 4; i++)
#pragma unroll
        for (int j = 0; j < 4; j++) acc[i][j] = zero;

    const int c0 = w * 2, c1 = w * 2 + 1;
    const int ar0 = c0 * 16 + (l >> 2), ar1 = c1 * 16 + (l >> 2);
    // swizzled source col-group: stored group l&3 holds global group (l&3)^((l>>3)&3)
    const int acs = (((l & 3) ^ ((l >> 3) & 3)) << 3);
    // read selector: global k-group `quad` lives at stored group quad^((lr>>1)&3)
    const int sel = ((quad ^ ((lr >> 1) & 3)) << 3);

    const unsigned short* aS0 = A + (size_t)(m0 + ar0) * D_DIM + acs;
    const unsigned short* aS1 = A + (size_t)(m0 + ar1) * D_DIM + acs;
    const unsigned short* bS0 = W + (size_t)(n0 + ar0) * D_DIM + acs;
    const unsigned short* bS1 = W + (size_t)(n0 + ar1) * D_DIM + acs;

#define PGLDS(src, dst)                                                                    \
    __builtin_amdgcn_global_load_lds((const __attribute__((address_space(1))) void*)(src), \
                                     (__attribute__((address_space(3))) void*)(dst), 16, 0, 0)

    const int NT = D_DIM / 32;  // 32
    // prologue: stage k-tiles 0 and 1 into bufs 0,1 (8 GLDS outstanding)
    PGLDS(aS0, &Asm[0][c0 * 512]);
    PGLDS(aS1, &Asm[0][c1 * 512]);
    PGLDS(bS0, &Bsm[0][c0 * 512]);
    PGLDS(bS1, &Bsm[0][c1 * 512]);
    aS0 += 32; aS1 += 32; bS0 += 32; bS1 += 32;
    PGLDS(aS0, &Asm[1][c0 * 512]);
    PGLDS(aS1, &Asm[1][c1 * 512]);
    PGLDS(bS0, &Bsm[1][c0 * 512]);
    PGLDS(bS1, &Bsm[1][c1 * 512]);
    aS0 += 32; aS1 += 32; bS0 += 32; bS1 += 32;

    int cur = 0;
    for (int kt = 0; kt < NT; ++kt) {
        // counted wait: oldest 4 outstanding (= GLDS(kt)) done; GLDS(kt+1) stays in flight.
        if (kt + 1 < NT)
            asm volatile("s_waitcnt vmcnt(4) lgkmcnt(0)" ::: "memory");
        else
            asm volatile("s_waitcnt vmcnt(0) lgkmcnt(0)" ::: "memory");
        __builtin_amdgcn_s_barrier();
        __builtin_amdgcn_sched_barrier(0);

        if (kt + 2 < NT) {
            int nb = cur + 2;
            if (nb >= 3) nb -= 3;
            PGLDS(aS0, &Asm[nb][c0 * 512]);
            PGLDS(aS1, &Asm[nb][c1 * 512]);
            PGLDS(bS0, &Bsm[nb][c0 * 512]);
            PGLDS(bS1, &Bsm[nb][c1 * 512]);
            aS0 += 32; aS1 += 32; bS0 += 32; bS1 += 32;
        }

        short8 af[4], bfr[4];
#pragma unroll
        for (int i = 0; i < 4; i++)
            af[i] = *(const short8*)&Asm[cur][(wm * 64 + i * 16 + lr) * 32 + sel];
#pragma unroll
        for (int j = 0; j < 4; j++)
            bfr[j] = *(const short8*)&Bsm[cur][(wn * 64 + j * 16 + lr) * 32 + sel];
#pragma unroll
        for (int i = 0; i < 4; i++)
#pragma unroll
            for (int j = 0; j < 4; j++)
                acc[i][j] = __builtin_amdgcn_mfma_f32_16x16x32_bf16(af[i], bfr[j], acc[i][j], 0, 0, 0);

        cur += 1;
        if (cur >= 3) cur = 0;
    }
#undef PGLDS

    if (z == 2) {
        // V: write transposed (B,H,dh,S). O == Vt here.
        const int bb = m0 >> 11;
        const int sl0 = (m0 & 2047) + wm * 64;
#pragma unroll
        for (int j = 0; j < 4; j++) {
            const int gn = n0 + wn * 64 + j * 16 + lr;
            const float bj = bias[gn];
            unsigned short* vrow =
                O + (size_t)((bb * NHEAD + (gn >> 6)) * DH + (gn & 63)) * S_LEN;
#pragma unroll
            for (int i = 0; i < 4; i++) {
                const int sl = sl0 + i * 16 + quad * 4;
                const unsigned int w0 =
                    ((unsigned int)f2bf(fmaxf(acc[i][j][1] + bj, 0.f)) << 16) |
                    f2bf(fmaxf(acc[i][j][0] + bj, 0.f));
                const unsigned int w1 =
                    ((unsigned int)f2bf(fmaxf(acc[i][j][3] + bj, 0.f)) << 16) |
                    f2bf(fmaxf(acc[i][j][2] + bj, 0.f));
                u32x2 pk = {w0, w1};
                *(u32x2*)(vrow + sl) = pk;
            }
        }
    } else {
        const float oscale = (z == 0) ? QSCALE : 1.0f;
#pragma unroll
        for (int j = 0; j < 4; j++) {
            const int gn = n0 + wn * 64 + j * 16 + lr;
            const float bj = bias[gn];
#pragma unroll
            for (int i = 0; i < 4; i++) {
                const int gmb = m0 + wm * 64 + i * 16 + quad * 4;
#pragma unroll
                for (int r = 0; r < 4; r++) {
                    float v = fmaxf(acc[i][j][r] + bj, 0.f) * oscale;
                    O[(size_t)(gmb + r) * D_DIM + gn] = f2bf(v);
                }
            }
        }
    }
}

// ---------------- flash attention: R5 single-barrier distance-1 pipeline ---------------
// grid (63, H, B) = 2016 blocks. 64-row q-tiles, wave = 16 q-rows. LDS 32768 B (5/CU).
// K AND V double-buffered; K(kt+1),V(kt+1) GLDS issued right after the ONE loop-top
// __syncthreads (writes go to alt buffers; hazards separated by the barrier+lgkmcnt).
// PV reads V resident since loop top -> old B2 (V drain) deleted; prefetch has a full
// tile (QK+softmax+PV) in flight. Swapped-QK^T zero-LDS P path as R2.
__global__ __launch_bounds__(256) void attn_kernel(
    const unsigned short* __restrict__ Qb, const unsigned short* __restrict__ Kb,
    const unsigned short* __restrict__ Vt, const float* __restrict__ km_pen,
    unsigned short* __restrict__ oP0, unsigned short* __restrict__ oP1,
    unsigned short* __restrict__ oP2, float* __restrict__ lP) {
    __shared__ __align__(16) unsigned short Ks[2][64 * 64];
    __shared__ __align__(16) unsigned short Vs[2][64 * 64];

    const int w = threadIdx.x >> 6, l = threadIdx.x & 63;
    const int quad = l >> 4, lr = l & 15;
    const int h = blockIdx.y, b = blockIdx.z;
    const float NEGF = -4294967295.0f;

    // ---- work assignment (LPT: longest first) ----
    int qt, sp;
    const int x = blockIdx.x;
    int ns;
    if (x < 30) { qt = 31 - x / 3; sp = x % 3; ns = 3; }
    else if (x < 52) { int y = x - 30; qt = 21 - y / 2; sp = y % 2; ns = 2; }
    else { qt = 62 - x; sp = 0; ns = 1; }
    const int T = qt + 1;
    const int lo = sp * T / ns, hi = (sp + 1) * T / ns;

    const int q0 = qt * 64;
    const int qbase = q0 + w * 16;

    const int cA = w * 128 + l;
    const int cB = w * 128 + 64 + l;
    const int keyA = cA >> 3, cbA = (cA & 7) ^ (keyA & 7);
    const int keyB = cB >> 3, cbB = (cB & 7) ^ (keyB & 7);
    const unsigned short* Krow = Kb + (size_t)b * S_LEN * D_DIM + h * DH;
    const unsigned short* Vrow = Vt + (size_t)(b * NHEAD + h) * DH * S_LEN;

    // incremental staging pointers (advance per tile)
    const unsigned short* kSA = Krow + (size_t)(lo * 64 + keyA) * D_DIM + cbA * 8;
    const unsigned short* kSB = Krow + (size_t)(lo * 64 + keyB) * D_DIM + cbB * 8;
    const unsigned short* vSA = Vrow + (size_t)keyA * S_LEN + lo * 64 + cbA * 8;
    const unsigned short* vSB = Vrow + (size_t)keyB * S_LEN + lo * 64 + cbB * 8;
    const float* kmrow = km_pen + b * S_LEN + lo * 64 + l;

    unsigned short* const kD0 = &Ks[0][(w * 128) * 8];
    unsigned short* const kD1 = &Ks[0][(w * 128 + 64) * 8];
    unsigned short* const kE0 = &Ks[1][(w * 128) * 8];
    unsigned short* const kE1 = &Ks[1][(w * 128 + 64) * 8];
    unsigned short* const vD0 = &Vs[0][(w * 128) * 8];
    unsigned short* const vD1 = &Vs[0][(w * 128 + 64) * 8];
    unsigned short* const vE0 = &Vs[1][(w * 128) * 8];
    unsigned short* const vE1 = &Vs[1][(w * 128 + 64) * 8];

    const unsigned short* qptr = Qb + (size_t)(b * S_LEN + qbase + lr) * D_DIM + h * DH + quad * 8;
    const short8 qf0 = *(const short8*)(qptr);
    const short8 qf1 = *(const short8*)(qptr + 32);

    f32x4 zero = {0.f, 0.f, 0.f, 0.f};
    f32x4 o[4];
#pragma unroll
    for (int j = 0; j < 4; j++) o[j] = zero;
    float l_loc = 0.f;

    const int swz0 = quad ^ (lr & 7);
    const int swz1 = (quad + 4) ^ (lr & 7);

    // V b128 read base: lane (quad,lr) reads group (d=16j+lr, sc=4ks+m(quad)),
    // m(quad)=bitrev2(quad); byte = lr*128 + ((m^(lr&7))<<4), ks toggles bit 6.
    const int mq = ((quad & 1) << 1) | (quad >> 1);
    const int voff0 = lr * 128 + ((mq ^ (lr & 7)) << 4);
    const char* const Vsb = (const char*)&Vs[0][0];
    const int thr = w * 16 + lr - quad * 4;

#define GLDS(src, dst)                                                                  \
    __builtin_amdgcn_global_load_lds((const __attribute__((address_space(1))) void*)(src), \
                                     (__attribute__((address_space(3))) void*)(dst), 16, 0, 0)

    // prologue: stage K(lo)->Ks[0], V(lo)->Vs[0]
    GLDS(kSA, kD0);
    GLDS(kSB, kD1);
    kSA += 64 * D_DIM;
    kSB += 64 * D_DIM;
    GLDS(vSA, vD0);
    GLDS(vSB, vD1);
    vSA += 64;
    vSB += 64;

    for (int kt = lo; kt < hi; ++kt) {
        const int cur = (kt - lo) & 1;
        __syncthreads();  // ONE barrier: drains K(kt),V(kt); prev-tile LDS reads retired
        const float kmsel = *kmrow;
        kmrow += 64;

        if (kt + 1 < hi) {  // prefetch K(kt+1),V(kt+1) into alt buffers
            if (cur) { GLDS(kSA, kD0); GLDS(kSB, kD1); GLDS(vSA, vD0); GLDS(vSB, vD1); }
            else     { GLDS(kSA, kE0); GLDS(kSB, kE1); GLDS(vSA, vE0); GLDS(vSB, vE1); }
            kSA += 64 * D_DIM;
            kSB += 64 * D_DIM;
            vSA += 64;
            vSB += 64;
        }

        // ---- scores, swapped operands: C[row=key-in-16][col=q=lr] ----
        f32x4 sc[4];
#pragma unroll
        for (int nf = 0; nf < 4; nf++) {
            const int key = nf * 16 + lr;
            const short8 kf0 = *(const short8*)&Ks[cur][(key * 8 + swz0) * 8];
            const short8 kf1 = *(const short8*)&Ks[cur][(key * 8 + swz1) * 8];
            f32x4 z = zero;
            z = __builtin_amdgcn_mfma_f32_16x16x32_bf16(kf0, qf0, z, 0, 0, 0);
            z = __builtin_amdgcn_mfma_f32_16x16x32_bf16(kf1, qf1, z, 0, 0, 0);
            sc[nf] = z;
        }

        const unsigned long long kb = __ballot(kmsel != 0.0f);

        // ---- softmax: bare exp2 (scores bounded); causal only on diagonal tile ----
        float e[4][4];
        if (kt == qt) {
#pragma unroll
            for (int nf = 0; nf < 4; nf++)
#pragma unroll
                for (int r = 0; r < 4; r++)
                    e[nf][r] = (nf * 16 + r <= thr) ? sc[nf][r] : NEGF;
        } else {
#pragma unroll
            for (int nf = 0; nf < 4; nf++)
#pragma unroll
                for (int r = 0; r < 4; r++) e[nf][r] = sc[nf][r];
        }
        if (kb) {  // wave-uniform; cold path (key padding mask present)
#pragma unroll
            for (int nf = 0; nf < 4; nf++) {
                const float4 kmq =
                    *(const float4*)(km_pen + (size_t)b * S_LEN + kt * 64 + nf * 16 + quad * 4);
                e[nf][0] += kmq.x;
                e[nf][1] += kmq.y;
                e[nf][2] += kmq.z;
                e[nf][3] += kmq.w;
            }
        }
#pragma unroll
        for (int nf = 0; nf < 4; nf++) {
#pragma unroll
            for (int r = 0; r < 4; r++) e[nf][r] = __builtin_amdgcn_exp2f(e[nf][r]);
            l_loc += (e[nf][0] + e[nf][1]) + (e[nf][2] + e[nf][3]);
        }

        // ---- pack P to bf16 in-register (trunc via byte-perm) ----
        unsigned int pw[8];
#pragma unroll
        for (int ks = 0; ks < 2; ks++)
#pragma unroll
            for (int p = 0; p < 4; p++) {
                const int nf = 2 * ks + (p >> 1);
                const int r0 = (p & 1) * 2;
                pw[ks * 4 + p] = __builtin_amdgcn_perm(
                    __builtin_bit_cast(unsigned int, e[nf][r0 + 1]),
                    __builtin_bit_cast(unsigned int, e[nf][r0]), 0x07060302u);
            }

        // ---- PV: permlane16_swap -> contiguous 8-key runs -> conflict-free b128 V ----
        const int vbase = cur << 13;  // Vs buffer select (8192 B per buffer)
#pragma unroll
        for (int ks = 0; ks < 2; ks++) {
            const u32x2 s0 = __builtin_amdgcn_permlane16_swap(pw[ks * 4 + 0], pw[ks * 4 + 2],
                                                              false, false);
            const u32x2 s1 = __builtin_amdgcn_permlane16_swap(pw[ks * 4 + 1], pw[ks * 4 + 3],
                                                              false, false);
            const u32x4 pq = {s0[0], s1[0], s0[1], s1[1]};
            const short8 pa = __builtin_bit_cast(short8, pq);
            const int off = vbase + (voff0 ^ (ks << 6));
#pragma unroll
            for (int j = 0; j < 4; j++) {
                const short8 vfj = *(const short8*)(Vsb + off + j * 2048);
                o[j] = __builtin_amdgcn_mfma_f32_16x16x32_bf16(pa, vfj, o[j], 0, 0, 0);
            }
        }
    }
#undef GLDS

    // ---- epilogue: bf16 O-partials + fp32 l-partials ----
    float ls = l_loc;
    ls += __shfl_xor(ls, 16);
    ls += __shfl_xor(ls, 32);
    unsigned short* oP = (sp == 0) ? oP0 : ((sp == 1) ? oP1 : oP2);
    if (l < 16)
        lP[sp * (BATCH * NHEAD * S_LEN) + (b * NHEAD + h) * S_LEN + qbase + lr] = ls;
#pragma unroll
    for (int r = 0; r < 4; r++) {
        const int q = qbase + quad * 4 + r;
#pragma unroll
        for (int j = 0; j < 4; j++) {
            oP[(size_t)(b * S_LEN + q) * D_DIM + h * DH + j * 16 + lr] = f2bf(o[j][r]);
        }
    }
}

// ---------------- residual + layernorm + split-K combine (up to 3 partials) ------------
__global__ __launch_bounds__(256) void ln_kernel(
    const unsigned short* __restrict__ oP0, const unsigned short* __restrict__ oP1,
    const unsigned short* __restrict__ oP2, const float* __restrict__ lP,
    const float* __restrict__ qmask, const float* __restrict__ queries,
    const float* __restrict__ gamma, const float* __restrict__ beta,
    float* __restrict__ out) {
    const int row = blockIdx.x;
    const int t = threadIdx.x;
    const int b = row >> 11, q = row & 2047;
    const int qt = q >> 6;  // 64-row q-tiles
    const int ns = (qt <= 10) ? 1 : ((qt <= 21) ? 2 : 3);
    const int h = t >> 4;
    const int lidx = (b * NHEAD + h) * S_LEN + q;
    const int LSTRIDE = BATCH * NHEAD * S_LEN;

    float ls = lP[lidx];
    const size_t ri = (size_t)row * 256 + t;
    const ushort4 a0 = ((const ushort4*)oP0)[ri];
    float sx = bf2f(a0.x), sy = bf2f(a0.y), sz = bf2f(a0.z), sw = bf2f(a0.w);
    if (ns > 1) {
        ls += lP[LSTRIDE + lidx];
        const ushort4 a1 = ((const ushort4*)oP1)[ri];
        sx += bf2f(a1.x); sy += bf2f(a1.y); sz += bf2f(a1.z); sw += bf2f(a1.w);
    }
    if (ns > 2) {
        ls += lP[2 * LSTRIDE + lidx];
        const ushort4 a2 = ((const ushort4*)oP2)[ri];
        sx += bf2f(a2.x); sy += bf2f(a2.y); sz += bf2f(a2.z); sw += bf2f(a2.w);
    }
    const float qmr = qmask[row];
    const float inv0 = (ls > 0.f) ? qmr / ls : 0.f;

    const float4 qv = ((const float4*)(queries + (size_t)row * D_DIM))[t];
    float4 x;
    x.x = sx * inv0 + qv.x;
    x.y = sy * inv0 + qv.y;
    x.z = sz * inv0 + qv.z;
    x.w = sw * inv0 + qv.w;

    float s = x.x + x.y + x.z + x.w;
    float sq = x.x * x.x + x.y * x.y + x.z * x.z + x.w * x.w;
    for (int o = 1; o < 64; o <<= 1) { s += __shfl_xor(s, o); sq += __shfl_xor(sq, o); }
    __shared__ float rs[4], rq[4];
    const int w = t >> 6;
    if ((t & 63) == 0) { rs[w] = s; rq[w] = sq; }
    __syncthreads();
    s = rs[0] + rs[1] + rs[2] + rs[3];
    sq = rq[0] + rq[1] + rq[2] + rq[3];
    const float mean = s * (1.0f / 1024.0f);
    float var = (sq - s * mean) * (1.0f / 1023.0f);
    var = fmaxf(var, 0.f);
    const float inv = 1.0f / (sqrtf(var) + 1e-8f);
    const float4 g = ((const float4*)gamma)[t];
    const float4 bb = ((const float4*)beta)[t];
    float4 y;
    y.x = g.x * (x.x - mean) * inv + bb.x;
    y.y = g.y * (x.y - mean) * inv + bb.y;
    y.z = g.z * (x.z - mean) * inv + bb.z;
    y.w = g.w * (x.w - mean) * inv + bb.w;
    ((float4*)(out + (size_t)row * D_DIM))[t] = y;
}

extern "C" void kernel_launch(void* const* d_in, const int* in_sizes, int n_in, void* d_out,
                              int out_size, void* d_ws, size_t ws_size, hipStream_t stream) {
    const float* queries = (const float*)d_in[0];
    const float* keys = (const float*)d_in[1];
    const float* values = (const float*)d_in[2];
    const float* Wq = (const float*)d_in[3];
    const float* bq = (const float*)d_in[4];
    const float* Wk = (const float*)d_in[5];
    const float* bk = (const float*)d_in[6];
    const float* Wv = (const float*)d_in[7];
    const float* bv = (const float*)d_in[8];
    const float* gamma = (const float*)d_in[9];
    const float* beta = (const float*)d_in[10];
    float* out = (float*)d_out;
    char* ws = (char*)d_ws;

    const size_t MB = 1048576;
    unsigned short* qin = (unsigned short*)(ws + 0);
    unsigned short* kin = (unsigned short*)(ws + 8 * MB);
    unsigned short* vin = (unsigned short*)(ws + 16 * MB);
    unsigned short* wqb = (unsigned short*)(ws + 24 * MB);
    unsigned short* wkb = (unsigned short*)(ws + 26 * MB);
    unsigned short* wvb = (unsigned short*)(ws + 28 * MB);
    unsigned short* Qb = (unsigned short*)(ws + 30 * MB);
    unsigned short* Kb = (unsigned short*)(ws + 38 * MB);
    unsigned short* Vt = (unsigned short*)(ws + 46 * MB);    // proj z==2 writes transposed
    unsigned short* oP0 = (unsigned short*)(ws + 16 * MB);   // aliases vin (dead after proj)
    unsigned short* oP1 = (unsigned short*)(ws + 56 * MB);
    unsigned short* oP2 = (unsigned short*)(ws + 8 * MB);    // aliases kin (dead after proj)
    float* qm = (float*)(ws + 54 * MB);
    float* km = (float*)(ws + 54 * MB + 16384);
    float* lP = (float*)(ws + 54 * MB + 32768);  // 3 x 65536 fp32 = 768KB

    cvt_all_kernel<<<dim3(NROWS + D_DIM, 3), 256, 0, stream>>>(
        queries, keys, values, Wq, Wk, Wv, qin, kin, vin, wqb, wkb, wvb, qm, km);

    proj_kernel<<<768, 256, 0, stream>>>(
        qin, kin, vin, wqb, wkb, wvb, bq, bk, bv, Qb, Kb, Vt);

    attn_kernel<<<dim3(63, NHEAD, BATCH), 256, 0, stream>>>(Qb, Kb, Vt, km, oP0, oP1, oP2, lP);

    ln_kernel<<<NROWS, 256, 0, stream>>>(oP0, oP1, oP2, lP, qm, queries, gamma, beta, out);
}

// Round 7
// 196.073 us; speedup vs baseline: 1.0781x; 1.0781x over previous
//
#include <hip/hip_runtime.h>

#define S_LEN 2048
#define D_DIM 1024
#define NHEAD 16
#define DH 64
#define BATCH 2
#define NROWS (BATCH * S_LEN)  // 4096
#define QSCALE 0.18033688011112042f  // 0.125 * log2(e): scores land in log2 domain

typedef __attribute__((ext_vector_type(8))) short short8;
typedef __attribute__((ext_vector_type(4))) float f32x4;
typedef __attribute__((ext_vector_type(2))) unsigned int u32x2;
typedef __attribute__((ext_vector_type(4))) unsigned int u32x4;

static __device__ __forceinline__ unsigned short f2bf(float f) {
    unsigned int u = __builtin_bit_cast(unsigned int, f);
    u += 0x7fffu + ((u >> 16) & 1u);
    return (unsigned short)(u >> 16);
}
static __device__ __forceinline__ float bf2f(unsigned short h) {
    unsigned int u = ((unsigned int)h) << 16;
    return __builtin_bit_cast(float, u);
}

// ---------------- fp32 -> bf16 convert (inputs + weights) + fused padding masks --------
__global__ __launch_bounds__(256) void cvt_all_kernel(
    const float* __restrict__ s0, const float* __restrict__ s1, const float* __restrict__ s2,
    const float* __restrict__ w0, const float* __restrict__ w1, const float* __restrict__ w2,
    unsigned short* __restrict__ d0, unsigned short* __restrict__ d1,
    unsigned short* __restrict__ d2, unsigned short* __restrict__ e0,
    unsigned short* __restrict__ e1, unsigned short* __restrict__ e2,
    float* __restrict__ qm, float* __restrict__ km) {
    const int y = blockIdx.y;
    const int row = blockIdx.x;
    const int t = threadIdx.x;
    const float* src;
    unsigned short* dst;
    size_t i;
    if (row < NROWS) {
        src = y == 0 ? s0 : (y == 1 ? s1 : s2);
        dst = y == 0 ? d0 : (y == 1 ? d1 : d2);
        i = (size_t)row * 256 + t;
    } else {
        src = y == 0 ? w0 : (y == 1 ? w1 : w2);
        dst = y == 0 ? e0 : (y == 1 ? e1 : e2);
        i = (size_t)(row - NROWS) * 256 + t;
    }
    float4 v = ((const float4*)src)[i];
    ushort4 o;
    o.x = f2bf(v.x); o.y = f2bf(v.y); o.z = f2bf(v.z); o.w = f2bf(v.w);
    ((ushort4*)dst)[i] = o;
    if (row < NROWS && y < 2) {
        float s = v.x + v.y + v.z + v.w;
        for (int off = 1; off < 64; off <<= 1) s += __shfl_xor(s, off);
        __shared__ float red[4];
        const int w = t >> 6;
        if ((t & 63) == 0) red[w] = s;
        __syncthreads();
        if (t == 0) {
            float tt = red[0] + red[1] + red[2] + red[3];
            if (y == 0)
                qm[row] = (tt != 0.0f) ? 1.0f : 0.0f;
            else
                km[row] = (tt != 0.0f) ? 0.0f : -4294967295.0f;
        }
    }
}

// ---------------- fused QKV projection: O = relu(A @ W^T + b), bf16 MFMA ----------------
// R4 distance-2 pipeline (3 LDS bufs, counted vmcnt(4), GLDS(kt+2) issued at iter kt).
// R6/R7: z==2 (V) transposes the 128x128 output tile THROUGH LDS (reusing the 48KB
// staging buffer, XOR-swizzled 16B groups) then writes Vt (B,H,dh,S) in 256B contiguous
// segments. R7 fix: read-back is 8 passes (32KB tile / 4KB-per-pass), not 16 — R6's
// passes 8..15 wrote out-of-range rows into other heads' Vt (absmax 2.71 fail).
__global__ __launch_bounds__(256) void proj_kernel(
    const unsigned short* __restrict__ A0, const unsigned short* __restrict__ A1,
    const unsigned short* __restrict__ A2, const unsigned short* __restrict__ W0,
    const unsigned short* __restrict__ W1, const unsigned short* __restrict__ W2,
    const float* __restrict__ b0, const float* __restrict__ b1, const float* __restrict__ b2,
    unsigned short* __restrict__ O0, unsigned short* __restrict__ O1,
    unsigned short* __restrict__ O2) {
    const int u = blockIdx.x;
    const int n = u / 96;
    const int rem = u % 96;
    const int m = rem / 3;
    const int z = rem % 3;
    const unsigned short* A;
    const unsigned short* W;
    const float* bias;
    unsigned short* O;
    if (z == 0) { A = A0; W = W0; bias = b0; O = O0; }
    else if (z == 1) { A = A1; W = W1; bias = b1; O = O1; }
    else { A = A2; W = W2; bias = b2; O = O2; }

    // single 48KB pool: Asm = SMEM[0..3*4096), Bsm = SMEM[3*4096..6*4096)
    __shared__ __align__(16) unsigned short SMEM[6 * 128 * 32];
    unsigned short* const Asm = SMEM;
    unsigned short* const Bsm = SMEM + 3 * 4096;

    const int t = threadIdx.x;
    const int w = t >> 6, l = t & 63;
    const int quad = l >> 4, lr = l & 15;
    const int wm = w >> 1, wn = w & 1;
    const int m0 = m * 128, n0 = n * 128;

    f32x4 zero = {0.f, 0.f, 0.f, 0.f};
    f32x4 acc[4][4];
#pragma unroll
    for (int i = 0; i < 4; i++)
#pragma unroll
        for (int j = 0; j < 4; j++) acc[i][j] = zero;

    const int c0 = w * 2, c1 = w * 2 + 1;
    const int ar0 = c0 * 16 + (l >> 2), ar1 = c1 * 16 + (l >> 2);
    // swizzled source col-group: stored group l&3 holds global group (l&3)^((l>>3)&3)
    const int acs = (((l & 3) ^ ((l >> 3) & 3)) << 3);
    // read selector: global k-group `quad` lives at stored group quad^((lr>>1)&3)
    const int sel = ((quad ^ ((lr >> 1) & 3)) << 3);

    const unsigned short* aS0 = A + (size_t)(m0 + ar0) * D_DIM + acs;
    const unsigned short* aS1 = A + (size_t)(m0 + ar1) * D_DIM + acs;
    const unsigned short* bS0 = W + (size_t)(n0 + ar0) * D_DIM + acs;
    const unsigned short* bS1 = W + (size_t)(n0 + ar1) * D_DIM + acs;

#define PGLDS(src, dst)                                                                    \
    __builtin_amdgcn_global_load_lds((const __attribute__((address_space(1))) void*)(src), \
                                     (__attribute__((address_space(3))) void*)(dst), 16, 0, 0)

    const int NT = D_DIM / 32;  // 32
    // prologue: stage k-tiles 0 and 1 into bufs 0,1 (8 GLDS outstanding)
    PGLDS(aS0, &Asm[0 * 4096 + c0 * 512]);
    PGLDS(aS1, &Asm[0 * 4096 + c1 * 512]);
    PGLDS(bS0, &Bsm[0 * 4096 + c0 * 512]);
    PGLDS(bS1, &Bsm[0 * 4096 + c1 * 512]);
    aS0 += 32; aS1 += 32; bS0 += 32; bS1 += 32;
    PGLDS(aS0, &Asm[1 * 4096 + c0 * 512]);
    PGLDS(aS1, &Asm[1 * 4096 + c1 * 512]);
    PGLDS(bS0, &Bsm[1 * 4096 + c0 * 512]);
    PGLDS(bS1, &Bsm[1 * 4096 + c1 * 512]);
    aS0 += 32; aS1 += 32; bS0 += 32; bS1 += 32;

    int cur = 0;
    for (int kt = 0; kt < NT; ++kt) {
        // counted wait: oldest 4 outstanding (= GLDS(kt)) done; GLDS(kt+1) stays in flight.
        if (kt + 1 < NT)
            asm volatile("s_waitcnt vmcnt(4) lgkmcnt(0)" ::: "memory");
        else
            asm volatile("s_waitcnt vmcnt(0) lgkmcnt(0)" ::: "memory");
        __builtin_amdgcn_s_barrier();
        __builtin_amdgcn_sched_barrier(0);

        if (kt + 2 < NT) {
            int nb = cur + 2;
            if (nb >= 3) nb -= 3;
            PGLDS(aS0, &Asm[nb * 4096 + c0 * 512]);
            PGLDS(aS1, &Asm[nb * 4096 + c1 * 512]);
            PGLDS(bS0, &Bsm[nb * 4096 + c0 * 512]);
            PGLDS(bS1, &Bsm[nb * 4096 + c1 * 512]);
            aS0 += 32; aS1 += 32; bS0 += 32; bS1 += 32;
        }

        short8 af[4], bfr[4];
#pragma unroll
        for (int i = 0; i < 4; i++)
            af[i] = *(const short8*)&Asm[cur * 4096 + (wm * 64 + i * 16 + lr) * 32 + sel];
#pragma unroll
        for (int j = 0; j < 4; j++)
            bfr[j] = *(const short8*)&Bsm[cur * 4096 + (wn * 64 + j * 16 + lr) * 32 + sel];
#pragma unroll
        for (int i = 0; i < 4; i++)
#pragma unroll
            for (int j = 0; j < 4; j++)
                acc[i][j] = __builtin_amdgcn_mfma_f32_16x16x32_bf16(af[i], bfr[j], acc[i][j], 0, 0, 0);

        cur += 1;
        if (cur >= 3) cur = 0;
    }
#undef PGLDS

    if (z == 2) {
        // V epilogue: transpose tile through LDS, write Vt (B,H,dh,S) coalesced.
        __syncthreads();  // all k-loop LDS reads retired before reuse
        char* const T = (char*)SMEM;  // 128 rows (n_local) x 256 B (m_local), XOR-swizzled
        const int bb = m0 >> 11;
        const int sl0 = m0 & 2047;
#pragma unroll
        for (int j = 0; j < 4; j++) {
            const int nl = wn * 64 + j * 16 + lr;
            const float bj = bias[n0 + nl];
            char* const Trow = T + nl * 256;
            const int xr = nl & 7;
#pragma unroll
            for (int i = 0; i < 4; i++) {
                const int mb = wm * 128 + i * 32 + quad * 8;  // byte off = m_local*2
                const int g = mb >> 4, wo = mb & 15;
                const unsigned int w0 =
                    ((unsigned int)f2bf(fmaxf(acc[i][j][1] + bj, 0.f)) << 16) |
                    f2bf(fmaxf(acc[i][j][0] + bj, 0.f));
                const unsigned int w1 =
                    ((unsigned int)f2bf(fmaxf(acc[i][j][3] + bj, 0.f)) << 16) |
                    f2bf(fmaxf(acc[i][j][2] + bj, 0.f));
                u32x2 pk = {w0, w1};
                *(u32x2*)(Trow + ((g ^ xr) << 4) + wo) = pk;
            }
        }
        __syncthreads();
#pragma unroll
        for (int p = 0; p < 8; p++) {  // 128 rows x 256B = 32KB; 4KB per pass
            const int idx = p * 256 + t;
            const int row = idx >> 4;  // n_local (0..127)
            const int cg = idx & 15;   // 16B col group
            const short8 vv = *(const short8*)(T + row * 256 + ((cg ^ (row & 7)) << 4));
            const int gn = n0 + row;
            unsigned short* dst =
                O + (size_t)((bb * NHEAD + (gn >> 6)) * DH + (gn & 63)) * S_LEN + sl0 + cg * 8;
            *(short8*)dst = vv;
        }
    } else {
        const float oscale = (z == 0) ? QSCALE : 1.0f;
#pragma unroll
        for (int j = 0; j < 4; j++) {
            const int gn = n0 + wn * 64 + j * 16 + lr;
            const float bj = bias[gn];
#pragma unroll
            for (int i = 0; i < 4; i++) {
                const int gmb = m0 + wm * 64 + i * 16 + quad * 4;
#pragma unroll
                for (int r = 0; r < 4; r++) {
                    float v = fmaxf(acc[i][j][r] + bj, 0.f) * oscale;
                    O[(size_t)(gmb + r) * D_DIM + gn] = f2bf(v);
                }
            }
        }
    }
}

// ---------------- flash attention: R5 single-barrier distance-1 pipeline ---------------
// grid (63, H, B) = 2016 blocks. 64-row q-tiles, wave = 16 q-rows. LDS 32768 B (5/CU).
// K AND V double-buffered; K(kt+1),V(kt+1) GLDS issued right after the ONE loop-top
// __syncthreads (writes go to alt buffers; hazards separated by the barrier+lgkmcnt).
// PV reads V resident since loop top. Swapped-QK^T zero-LDS P path as R2.
__global__ __launch_bounds__(256) void attn_kernel(
    const unsigned short* __restrict__ Qb, const unsigned short* __restrict__ Kb,
    const unsigned short* __restrict__ Vt, const float* __restrict__ km_pen,
    unsigned short* __restrict__ oP0, unsigned short* __restrict__ oP1,
    unsigned short* __restrict__ oP2, float* __restrict__ lP) {
    __shared__ __align__(16) unsigned short Ks[2][64 * 64];
    __shared__ __align__(16) unsigned short Vs[2][64 * 64];

    const int w = threadIdx.x >> 6, l = threadIdx.x & 63;
    const int quad = l >> 4, lr = l & 15;
    const int h = blockIdx.y, b = blockIdx.z;
    const float NEGF = -4294967295.0f;

    // ---- work assignment (LPT: longest first) ----
    int qt, sp;
    const int x = blockIdx.x;
    int ns;
    if (x < 30) { qt = 31 - x / 3; sp = x % 3; ns = 3; }
    else if (x < 52) { int y = x - 30; qt = 21 - y / 2; sp = y % 2; ns = 2; }
    else { qt = 62 - x; sp = 0; ns = 1; }
    const int T = qt + 1;
    const int lo = sp * T / ns, hi = (sp + 1) * T / ns;

    const int q0 = qt * 64;
    const int qbase = q0 + w * 16;

    const int cA = w * 128 + l;
    const int cB = w * 128 + 64 + l;
    const int keyA = cA >> 3, cbA = (cA & 7) ^ (keyA & 7);
    const int keyB = cB >> 3, cbB = (cB & 7) ^ (keyB & 7);
    const unsigned short* Krow = Kb + (size_t)b * S_LEN * D_DIM + h * DH;
    const unsigned short* Vrow = Vt + (size_t)(b * NHEAD + h) * DH * S_LEN;

    // incremental staging pointers (advance per tile)
    const unsigned short* kSA = Krow + (size_t)(lo * 64 + keyA) * D_DIM + cbA * 8;
    const unsigned short* kSB = Krow + (size_t)(lo * 64 + keyB) * D_DIM + cbB * 8;
    const unsigned short* vSA = Vrow + (size_t)keyA * S_LEN + lo * 64 + cbA * 8;
    const unsigned short* vSB = Vrow + (size_t)keyB * S_LEN + lo * 64 + cbB * 8;
    const float* kmrow = km_pen + b * S_LEN + lo * 64 + l;

    unsigned short* const kD0 = &Ks[0][(w * 128) * 8];
    unsigned short* const kD1 = &Ks[0][(w * 128 + 64) * 8];
    unsigned short* const kE0 = &Ks[1][(w * 128) * 8];
    unsigned short* const kE1 = &Ks[1][(w * 128 + 64) * 8];
    unsigned short* const vD0 = &Vs[0][(w * 128) * 8];
    unsigned short* const vD1 = &Vs[0][(w * 128 + 64) * 8];
    unsigned short* const vE0 = &Vs[1][(w * 128) * 8];
    unsigned short* const vE1 = &Vs[1][(w * 128 + 64) * 8];

    const unsigned short* qptr = Qb + (size_t)(b * S_LEN + qbase + lr) * D_DIM + h * DH + quad * 8;
    const short8 qf0 = *(const short8*)(qptr);
    const short8 qf1 = *(const short8*)(qptr + 32);

    f32x4 zero = {0.f, 0.f, 0.f, 0.f};
    f32x4 o[4];
#pragma unroll
    for (int j = 0; j < 4; j++) o[j] = zero;
    float l_loc = 0.f;

    const int swz0 = quad ^ (lr & 7);
    const int swz1 = (quad + 4) ^ (lr & 7);

    // V b128 read base: lane (quad,lr) reads group (d=16j+lr, sc=4ks+m(quad)),
    // m(quad)=bitrev2(quad); byte = lr*128 + ((m^(lr&7))<<4), ks toggles bit 6.
    const int mq = ((quad & 1) << 1) | (quad >> 1);
    const int voff0 = lr * 128 + ((mq ^ (lr & 7)) << 4);
    const char* const Vsb = (const char*)&Vs[0][0];
    const int thr = w * 16 + lr - quad * 4;

#define GLDS(src, dst)                                                                  \
    __builtin_amdgcn_global_load_lds((const __attribute__((address_space(1))) void*)(src), \
                                     (__attribute__((address_space(3))) void*)(dst), 16, 0, 0)

    // prologue: stage K(lo)->Ks[0], V(lo)->Vs[0]
    GLDS(kSA, kD0);
    GLDS(kSB, kD1);
    kSA += 64 * D_DIM;
    kSB += 64 * D_DIM;
    GLDS(vSA, vD0);
    GLDS(vSB, vD1);
    vSA += 64;
    vSB += 64;

    for (int kt = lo; kt < hi; ++kt) {
        const int cur = (kt - lo) & 1;
        __syncthreads();  // ONE barrier: drains K(kt),V(kt); prev-tile LDS reads retired
        const float kmsel = *kmrow;
        kmrow += 64;

        if (kt + 1 < hi) {  // prefetch K(kt+1),V(kt+1) into alt buffers
            if (cur) { GLDS(kSA, kD0); GLDS(kSB, kD1); GLDS(vSA, vD0); GLDS(vSB, vD1); }
            else     { GLDS(kSA, kE0); GLDS(kSB, kE1); GLDS(vSA, vE0); GLDS(vSB, vE1); }
            kSA += 64 * D_DIM;
            kSB += 64 * D_DIM;
            vSA += 64;
            vSB += 64;
        }

        // ---- scores, swapped operands: C[row=key-in-16][col=q=lr] ----
        f32x4 sc[4];
#pragma unroll
        for (int nf = 0; nf < 4; nf++) {
            const int key = nf * 16 + lr;
            const short8 kf0 = *(const short8*)&Ks[cur][(key * 8 + swz0) * 8];
            const short8 kf1 = *(const short8*)&Ks[cur][(key * 8 + swz1) * 8];
            f32x4 z = zero;
            z = __builtin_amdgcn_mfma_f32_16x16x32_bf16(kf0, qf0, z, 0, 0, 0);
            z = __builtin_amdgcn_mfma_f32_16x16x32_bf16(kf1, qf1, z, 0, 0, 0);
            sc[nf] = z;
        }

        const unsigned long long kb = __ballot(kmsel != 0.0f);

        // ---- softmax: bare exp2 (scores bounded); causal only on diagonal tile ----
        float e[4][4];
        if (kt == qt) {
#pragma unroll
            for (int nf = 0; nf < 4; nf++)
#pragma unroll
                for (int r = 0; r < 4; r++)
                    e[nf][r] = (nf * 16 + r <= thr) ? sc[nf][r] : NEGF;
        } else {
#pragma unroll
            for (int nf = 0; nf < 4; nf++)
#pragma unroll
                for (int r = 0; r < 4; r++) e[nf][r] = sc[nf][r];
        }
        if (kb) {  // wave-uniform; cold path (key padding mask present)
#pragma unroll
            for (int nf = 0; nf < 4; nf++) {
                const float4 kmq =
                    *(const float4*)(km_pen + (size_t)b * S_LEN + kt * 64 + nf * 16 + quad * 4);
                e[nf][0] += kmq.x;
                e[nf][1] += kmq.y;
                e[nf][2] += kmq.z;
                e[nf][3] += kmq.w;
            }
        }
#pragma unroll
        for (int nf = 0; nf < 4; nf++) {
#pragma unroll
            for (int r = 0; r < 4; r++) e[nf][r] = __builtin_amdgcn_exp2f(e[nf][r]);
            l_loc += (e[nf][0] + e[nf][1]) + (e[nf][2] + e[nf][3]);
        }

        // ---- pack P to bf16 in-register (trunc via byte-perm) ----
        unsigned int pw[8];
#pragma unroll
        for (int ks = 0; ks < 2; ks++)
#pragma unroll
            for (int p = 0; p < 4; p++) {
                const int nf = 2 * ks + (p >> 1);
                const int r0 = (p & 1) * 2;
                pw[ks * 4 + p] = __builtin_amdgcn_perm(
                    __builtin_bit_cast(unsigned int, e[nf][r0 + 1]),
                    __builtin_bit_cast(unsigned int, e[nf][r0]), 0x07060302u);
            }

        // ---- PV: permlane16_swap -> contiguous 8-key runs -> conflict-free b128 V ----
        const int vbase = cur << 13;  // Vs buffer select (8192 B per buffer)
#pragma unroll
        for (int ks = 0; ks < 2; ks++) {
            const u32x2 s0 = __builtin_amdgcn_permlane16_swap(pw[ks * 4 + 0], pw[ks * 4 + 2],
                                                              false, false);
            const u32x2 s1 = __builtin_amdgcn_permlane16_swap(pw[ks * 4 + 1], pw[ks * 4 + 3],
                                                              false, false);
            const u32x4 pq = {s0[0], s1[0], s0[1], s1[1]};
            const short8 pa = __builtin_bit_cast(short8, pq);
            const int off = vbase + (voff0 ^ (ks << 6));
#pragma unroll
            for (int j = 0; j < 4; j++) {
                const short8 vfj = *(const short8*)(Vsb + off + j * 2048);
                o[j] = __builtin_amdgcn_mfma_f32_16x16x32_bf16(pa, vfj, o[j], 0, 0, 0);
            }
        }
    }
#undef GLDS

    // ---- epilogue: bf16 O-partials + fp32 l-partials ----
    float ls = l_loc;
    ls += __shfl_xor(ls, 16);
    ls += __shfl_xor(ls, 32);
    unsigned short* oP = (sp == 0) ? oP0 : ((sp == 1) ? oP1 : oP2);
    if (l < 16)
        lP[sp * (BATCH * NHEAD * S_LEN) + (b * NHEAD + h) * S_LEN + qbase + lr] = ls;
#pragma unroll
    for (int r = 0; r < 4; r++) {
        const int q = qbase + quad * 4 + r;
#pragma unroll
        for (int j = 0; j < 4; j++) {
            oP[(size_t)(b * S_LEN + q) * D_DIM + h * DH + j * 16 + lr] = f2bf(o[j][r]);
        }
    }
}

// ---------------- residual + layernorm + split-K combine (up to 3 partials) ------------
__global__ __launch_bounds__(256) void ln_kernel(
    const unsigned short* __restrict__ oP0, const unsigned short* __restrict__ oP1,
    const unsigned short* __restrict__ oP2, const float* __restrict__ lP,
    const float* __restrict__ qmask, const float* __restrict__ queries,
    const float* __restrict__ gamma, const float* __restrict__ beta,
    float* __restrict__ out) {
    const int row = blockIdx.x;
    const int t = threadIdx.x;
    const int b = row >> 11, q = row & 2047;
    const int qt = q >> 6;  // 64-row q-tiles
    const int ns = (qt <= 10) ? 1 : ((qt <= 21) ? 2 : 3);
    const int h = t >> 4;
    const int lidx = (b * NHEAD + h) * S_LEN + q;
    const int LSTRIDE = BATCH * NHEAD * S_LEN;

    float ls = lP[lidx];
    const size_t ri = (size_t)row * 256 + t;
    const ushort4 a0 = ((const ushort4*)oP0)[ri];
    float sx = bf2f(a0.x), sy = bf2f(a0.y), sz = bf2f(a0.z), sw = bf2f(a0.w);
    if (ns > 1) {
        ls += lP[LSTRIDE + lidx];
        const ushort4 a1 = ((const ushort4*)oP1)[ri];
        sx += bf2f(a1.x); sy += bf2f(a1.y); sz += bf2f(a1.z); sw += bf2f(a1.w);
    }
    if (ns > 2) {
        ls += lP[2 * LSTRIDE + lidx];
        const ushort4 a2 = ((const ushort4*)oP2)[ri];
        sx += bf2f(a2.x); sy += bf2f(a2.y); sz += bf2f(a2.z); sw += bf2f(a2.w);
    }
    const float qmr = qmask[row];
    const float inv0 = (ls > 0.f) ? qmr / ls : 0.f;

    const float4 qv = ((const float4*)(queries + (size_t)row * D_DIM))[t];
    float4 x;
    x.x = sx * inv0 + qv.x;
    x.y = sy * inv0 + qv.y;
    x.z = sz * inv0 + qv.z;
    x.w = sw * inv0 + qv.w;

    float s = x.x + x.y + x.z + x.w;
    float sq = x.x * x.x + x.y * x.y + x.z * x.z + x.w * x.w;
    for (int o = 1; o < 64; o <<= 1) { s += __shfl_xor(s, o); sq += __shfl_xor(sq, o); }
    __shared__ float rs[4], rq[4];
    const int w = t >> 6;
    if ((t & 63) == 0) { rs[w] = s; rq[w] = sq; }
    __syncthreads();
    s = rs[0] + rs[1] + rs[2] + rs[3];
    sq = rq[0] + rq[1] + rq[2] + rq[3];
    const float mean = s * (1.0f / 1024.0f);
    float var = (sq - s * mean) * (1.0f / 1023.0f);
    var = fmaxf(var, 0.f);
    const float inv = 1.0f / (sqrtf(var) + 1e-8f);
    const float4 g = ((const float4*)gamma)[t];
    const float4 bb = ((const float4*)beta)[t];
    float4 y;
    y.x = g.x * (x.x - mean) * inv + bb.x;
    y.y = g.y * (x.y - mean) * inv + bb.y;
    y.z = g.z * (x.z - mean) * inv + bb.z;
    y.w = g.w * (x.w - mean) * inv + bb.w;
    ((float4*)(out + (size_t)row * D_DIM))[t] = y;
}

extern "C" void kernel_launch(void* const* d_in, const int* in_sizes, int n_in, void* d_out,
                              int out_size, void* d_ws, size_t ws_size, hipStream_t stream) {
    const float* queries = (const float*)d_in[0];
    const float* keys = (const float*)d_in[1];
    const float* values = (const float*)d_in[2];
    const float* Wq = (const float*)d_in[3];
    const float* bq = (const float*)d_in[4];
    const float* Wk = (const float*)d_in[5];
    const float* bk = (const float*)d_in[6];
    const float* Wv = (const float*)d_in[7];
    const float* bv = (const float*)d_in[8];
    const float* gamma = (const float*)d_in[9];
    const float* beta = (const float*)d_in[10];
    float* out = (float*)d_out;
    char* ws = (char*)d_ws;

    const size_t MB = 1048576;
    unsigned short* qin = (unsigned short*)(ws + 0);
    unsigned short* kin = (unsigned short*)(ws + 8 * MB);
    unsigned short* vin = (unsigned short*)(ws + 16 * MB);
    unsigned short* wqb = (unsigned short*)(ws + 24 * MB);
    unsigned short* wkb = (unsigned short*)(ws + 26 * MB);
    unsigned short* wvb = (unsigned short*)(ws + 28 * MB);
    unsigned short* Qb = (unsigned short*)(ws + 30 * MB);
    unsigned short* Kb = (unsigned short*)(ws + 38 * MB);
    unsigned short* Vt = (unsigned short*)(ws + 46 * MB);    // proj z==2 writes transposed
    unsigned short* oP0 = (unsigned short*)(ws + 16 * MB);   // aliases vin (dead after proj)
    unsigned short* oP1 = (unsigned short*)(ws + 56 * MB);
    unsigned short* oP2 = (unsigned short*)(ws + 8 * MB);    // aliases kin (dead after proj)
    float* qm = (float*)(ws + 54 * MB);
    float* km = (float*)(ws + 54 * MB + 16384);
    float* lP = (float*)(ws + 54 * MB + 32768);  // 3 x 65536 fp32 = 768KB

    cvt_all_kernel<<<dim3(NROWS + D_DIM, 3), 256, 0, stream>>>(
        queries, keys, values, Wq, Wk, Wv, qin, kin, vin, wqb, wkb, wvb, qm, km);

    proj_kernel<<<768, 256, 0, stream>>>(
        qin, kin, vin, wqb, wkb, wvb, bq, bk, bv, Qb, Kb, Vt);

    attn_kernel<<<dim3(63, NHEAD, BATCH), 256, 0, stream>>>(Qb, Kb, Vt, km, oP0, oP1, oP2, lP);

    ln_kernel<<<NROWS, 256, 0, stream>>>(oP0, oP1, oP2, lP, qm, queries, gamma, beta, out);
}

// Round 8
// 190.833 us; speedup vs baseline: 1.1077x; 1.0275x over previous
//
#include <hip/hip_runtime.h>

#define S_LEN 2048
#define D_DIM 1024
#define NHEAD 16
#define DH 64
#define BATCH 2
#define NROWS (BATCH * S_LEN)  // 4096
#define QSCALE 0.18033688011112042f  // 0.125 * log2(e): scores land in log2 domain

typedef __attribute__((ext_vector_type(8))) short short8;
typedef __attribute__((ext_vector_type(4))) float f32x4;
typedef __attribute__((ext_vector_type(2))) unsigned int u32x2;
typedef __attribute__((ext_vector_type(4))) unsigned int u32x4;

static __device__ __forceinline__ unsigned short f2bf(float f) {
    unsigned int u = __builtin_bit_cast(unsigned int, f);
    u += 0x7fffu + ((u >> 16) & 1u);
    return (unsigned short)(u >> 16);
}
static __device__ __forceinline__ float bf2f(unsigned short h) {
    unsigned int u = ((unsigned int)h) << 16;
    return __builtin_bit_cast(float, u);
}

// ---------------- fp32 -> bf16 convert (inputs + weights) + fused padding masks --------
__global__ __launch_bounds__(256) void cvt_all_kernel(
    const float* __restrict__ s0, const float* __restrict__ s1, const float* __restrict__ s2,
    const float* __restrict__ w0, const float* __restrict__ w1, const float* __restrict__ w2,
    unsigned short* __restrict__ d0, unsigned short* __restrict__ d1,
    unsigned short* __restrict__ d2, unsigned short* __restrict__ e0,
    unsigned short* __restrict__ e1, unsigned short* __restrict__ e2,
    float* __restrict__ qm, float* __restrict__ km) {
    const int y = blockIdx.y;
    const int row = blockIdx.x;
    const int t = threadIdx.x;
    const float* src;
    unsigned short* dst;
    size_t i;
    if (row < NROWS) {
        src = y == 0 ? s0 : (y == 1 ? s1 : s2);
        dst = y == 0 ? d0 : (y == 1 ? d1 : d2);
        i = (size_t)row * 256 + t;
    } else {
        src = y == 0 ? w0 : (y == 1 ? w1 : w2);
        dst = y == 0 ? e0 : (y == 1 ? e1 : e2);
        i = (size_t)(row - NROWS) * 256 + t;
    }
    float4 v = ((const float4*)src)[i];
    ushort4 o;
    o.x = f2bf(v.x); o.y = f2bf(v.y); o.z = f2bf(v.z); o.w = f2bf(v.w);
    ((ushort4*)dst)[i] = o;
    if (row < NROWS && y < 2) {
        float s = v.x + v.y + v.z + v.w;
        for (int off = 1; off < 64; off <<= 1) s += __shfl_xor(s, off);
        __shared__ float red[4];
        const int w = t >> 6;
        if ((t & 63) == 0) red[w] = s;
        __syncthreads();
        if (t == 0) {
            float tt = red[0] + red[1] + red[2] + red[3];
            if (y == 0)
                qm[row] = (tt != 0.0f) ? 1.0f : 0.0f;
            else
                km[row] = (tt != 0.0f) ? 0.0f : -4294967295.0f;
        }
    }
}

// ---------------- fused QKV projection: O = relu(A @ W^T + b), bf16 MFMA ----------------
// R4 distance-2 pipeline (3 LDS bufs, counted vmcnt(4), GLDS(kt+2) issued at iter kt).
// z==2 (V) transposes the 128x128 output tile THROUGH LDS (XOR-swizzled 16B groups)
// then writes Vt (B,H,dh,S) in 256B contiguous segments (8 read-back passes).
__global__ __launch_bounds__(256) void proj_kernel(
    const unsigned short* __restrict__ A0, const unsigned short* __restrict__ A1,
    const unsigned short* __restrict__ A2, const unsigned short* __restrict__ W0,
    const unsigned short* __restrict__ W1, const unsigned short* __restrict__ W2,
    const float* __restrict__ b0, const float* __restrict__ b1, const float* __restrict__ b2,
    unsigned short* __restrict__ O0, unsigned short* __restrict__ O1,
    unsigned short* __restrict__ O2) {
    const int u = blockIdx.x;
    const int n = u / 96;
    const int rem = u % 96;
    const int m = rem / 3;
    const int z = rem % 3;
    const unsigned short* A;
    const unsigned short* W;
    const float* bias;
    unsigned short* O;
    if (z == 0) { A = A0; W = W0; bias = b0; O = O0; }
    else if (z == 1) { A = A1; W = W1; bias = b1; O = O1; }
    else { A = A2; W = W2; bias = b2; O = O2; }

    // single 48KB pool: Asm = SMEM[0..3*4096), Bsm = SMEM[3*4096..6*4096)
    __shared__ __align__(16) unsigned short SMEM[6 * 128 * 32];
    unsigned short* const Asm = SMEM;
    unsigned short* const Bsm = SMEM + 3 * 4096;

    const int t = threadIdx.x;
    const int w = t >> 6, l = t & 63;
    const int quad = l >> 4, lr = l & 15;
    const int wm = w >> 1, wn = w & 1;
    const int m0 = m * 128, n0 = n * 128;

    f32x4 zero = {0.f, 0.f, 0.f, 0.f};
    f32x4 acc[4][4];
#pragma unroll
    for (int i = 0; i < 4; i++)
#pragma unroll
        for (int j = 0; j < 4; j++) acc[i][j] = zero;

    const int c0 = w * 2, c1 = w * 2 + 1;
    const int ar0 = c0 * 16 + (l >> 2), ar1 = c1 * 16 + (l >> 2);
    const int acs = (((l & 3) ^ ((l >> 3) & 3)) << 3);
    const int sel = ((quad ^ ((lr >> 1) & 3)) << 3);

    const unsigned short* aS0 = A + (size_t)(m0 + ar0) * D_DIM + acs;
    const unsigned short* aS1 = A + (size_t)(m0 + ar1) * D_DIM + acs;
    const unsigned short* bS0 = W + (size_t)(n0 + ar0) * D_DIM + acs;
    const unsigned short* bS1 = W + (size_t)(n0 + ar1) * D_DIM + acs;

#define PGLDS(src, dst)                                                                    \
    __builtin_amdgcn_global_load_lds((const __attribute__((address_space(1))) void*)(src), \
                                     (__attribute__((address_space(3))) void*)(dst), 16, 0, 0)

    const int NT = D_DIM / 32;  // 32
    PGLDS(aS0, &Asm[0 * 4096 + c0 * 512]);
    PGLDS(aS1, &Asm[0 * 4096 + c1 * 512]);
    PGLDS(bS0, &Bsm[0 * 4096 + c0 * 512]);
    PGLDS(bS1, &Bsm[0 * 4096 + c1 * 512]);
    aS0 += 32; aS1 += 32; bS0 += 32; bS1 += 32;
    PGLDS(aS0, &Asm[1 * 4096 + c0 * 512]);
    PGLDS(aS1, &Asm[1 * 4096 + c1 * 512]);
    PGLDS(bS0, &Bsm[1 * 4096 + c0 * 512]);
    PGLDS(bS1, &Bsm[1 * 4096 + c1 * 512]);
    aS0 += 32; aS1 += 32; bS0 += 32; bS1 += 32;

    int cur = 0;
    for (int kt = 0; kt < NT; ++kt) {
        if (kt + 1 < NT)
            asm volatile("s_waitcnt vmcnt(4) lgkmcnt(0)" ::: "memory");
        else
            asm volatile("s_waitcnt vmcnt(0) lgkmcnt(0)" ::: "memory");
        __builtin_amdgcn_s_barrier();
        __builtin_amdgcn_sched_barrier(0);

        if (kt + 2 < NT) {
            int nb = cur + 2;
            if (nb >= 3) nb -= 3;
            PGLDS(aS0, &Asm[nb * 4096 + c0 * 512]);
            PGLDS(aS1, &Asm[nb * 4096 + c1 * 512]);
            PGLDS(bS0, &Bsm[nb * 4096 + c0 * 512]);
            PGLDS(bS1, &Bsm[nb * 4096 + c1 * 512]);
            aS0 += 32; aS1 += 32; bS0 += 32; bS1 += 32;
        }

        short8 af[4], bfr[4];
#pragma unroll
        for (int i = 0; i < 4; i++)
            af[i] = *(const short8*)&Asm[cur * 4096 + (wm * 64 + i * 16 + lr) * 32 + sel];
#pragma unroll
        for (int j = 0; j < 4; j++)
            bfr[j] = *(const short8*)&Bsm[cur * 4096 + (wn * 64 + j * 16 + lr) * 32 + sel];
#pragma unroll
        for (int i = 0; i < 4; i++)
#pragma unroll
            for (int j = 0; j < 4; j++)
                acc[i][j] = __builtin_amdgcn_mfma_f32_16x16x32_bf16(af[i], bfr[j], acc[i][j], 0, 0, 0);

        cur += 1;
        if (cur >= 3) cur = 0;
    }
#undef PGLDS

    if (z == 2) {
        // V epilogue: transpose tile through LDS, write Vt (B,H,dh,S) coalesced.
        __syncthreads();
        char* const T = (char*)SMEM;  // 128 rows (n_local) x 256 B (m_local), XOR-swizzled
        const int bb = m0 >> 11;
        const int sl0 = m0 & 2047;
#pragma unroll
        for (int j = 0; j < 4; j++) {
            const int nl = wn * 64 + j * 16 + lr;
            const float bj = bias[n0 + nl];
            char* const Trow = T + nl * 256;
            const int xr = nl & 7;
#pragma unroll
            for (int i = 0; i < 4; i++) {
                const int mb = wm * 128 + i * 32 + quad * 8;
                const int g = mb >> 4, wo = mb & 15;
                const unsigned int w0 =
                    ((unsigned int)f2bf(fmaxf(acc[i][j][1] + bj, 0.f)) << 16) |
                    f2bf(fmaxf(acc[i][j][0] + bj, 0.f));
                const unsigned int w1 =
                    ((unsigned int)f2bf(fmaxf(acc[i][j][3] + bj, 0.f)) << 16) |
                    f2bf(fmaxf(acc[i][j][2] + bj, 0.f));
                u32x2 pk = {w0, w1};
                *(u32x2*)(Trow + ((g ^ xr) << 4) + wo) = pk;
            }
        }
        __syncthreads();
#pragma unroll
        for (int p = 0; p < 8; p++) {  // 128 rows x 256B = 32KB; 4KB per pass
            const int idx = p * 256 + t;
            const int row = idx >> 4;
            const int cg = idx & 15;
            const short8 vv = *(const short8*)(T + row * 256 + ((cg ^ (row & 7)) << 4));
            const int gn = n0 + row;
            unsigned short* dst =
                O + (size_t)((bb * NHEAD + (gn >> 6)) * DH + (gn & 63)) * S_LEN + sl0 + cg * 8;
            *(short8*)dst = vv;
        }
    } else {
        const float oscale = (z == 0) ? QSCALE : 1.0f;
#pragma unroll
        for (int j = 0; j < 4; j++) {
            const int gn = n0 + wn * 64 + j * 16 + lr;
            const float bj = bias[gn];
#pragma unroll
            for (int i = 0; i < 4; i++) {
                const int gmb = m0 + wm * 64 + i * 16 + quad * 4;
#pragma unroll
                for (int r = 0; r < 4; r++) {
                    float v = fmaxf(acc[i][j][r] + bj, 0.f) * oscale;
                    O[(size_t)(gmb + r) * D_DIM + gn] = f2bf(v);
                }
            }
        }
    }
}

// ---------------- flash attention: R8 QBLK=128 (2 q-groups/wave, shared K/V frags) -----
// grid (24, H, B) = 768 blocks, LPT tables. 128-row q-tiles, wave = 2x16 q-rows.
// K/V fragments are wave-invariant: read ONCE per tile, feed 2 MFMAs each (both
// q-groups) -> LDS reads per q-row HALVED vs R7 (was 52% of attn time). Single-barrier
// distance-1 K+V double-buffer pipeline as R5. Diagonal 128-block = 2 k-tiles with
// per-group masking (fully-masked group -> exp2 -> 0, correct). ln ns-map: q>=1024 ? 2:1.
__global__ __launch_bounds__(256) void attn_kernel(
    const unsigned short* __restrict__ Qb, const unsigned short* __restrict__ Kb,
    const unsigned short* __restrict__ Vt, const float* __restrict__ km_pen,
    unsigned short* __restrict__ oP0, unsigned short* __restrict__ oP1,
    float* __restrict__ lP) {
    __shared__ __align__(16) unsigned short Ks[2][64 * 64];
    __shared__ __align__(16) unsigned short Vs[2][64 * 64];

    const int w = threadIdx.x >> 6, l = threadIdx.x & 63;
    const int quad = l >> 4, lr = l & 15;
    const int h = blockIdx.y, b = blockIdx.z;
    const float NEGF = -4294967295.0f;

    // ---- work assignment: 16 q-tiles (128 rows), T=2qt+2; qt>=8 split 2-way; LPT ----
    static const signed char QT_TAB[24] = {15, 15, 7, 14, 14, 13, 13, 6, 12, 12, 11, 11,
                                           5, 10, 10, 9, 9, 4, 8, 8, 3, 2, 1, 0};
    static const signed char SP_TAB[24] = {0, 1, 0, 0, 1, 0, 1, 0, 0, 1, 0, 1,
                                           0, 0, 1, 0, 1, 0, 0, 1, 0, 0, 0, 0};
    const int x = blockIdx.x;
    const int qt = QT_TAB[x], sp = SP_TAB[x];
    const int ns = (qt >= 8) ? 2 : 1;
    const int T = 2 * qt + 2;
    const int lo = sp * T / ns, hi = (sp + 1) * T / ns;

    const int q0 = qt * 128;
    const int qb0 = q0 + w * 16;        // group 0 rows (lower 64)
    const int qb1 = q0 + 64 + w * 16;   // group 1 rows (upper 64)

    const int cA = w * 128 + l;
    const int cB = w * 128 + 64 + l;
    const int keyA = cA >> 3, cbA = (cA & 7) ^ (keyA & 7);
    const int keyB = cB >> 3, cbB = (cB & 7) ^ (keyB & 7);
    const unsigned short* Krow = Kb + (size_t)b * S_LEN * D_DIM + h * DH;
    const unsigned short* Vrow = Vt + (size_t)(b * NHEAD + h) * DH * S_LEN;

    const unsigned short* kSA = Krow + (size_t)(lo * 64 + keyA) * D_DIM + cbA * 8;
    const unsigned short* kSB = Krow + (size_t)(lo * 64 + keyB) * D_DIM + cbB * 8;
    const unsigned short* vSA = Vrow + (size_t)keyA * S_LEN + lo * 64 + cbA * 8;
    const unsigned short* vSB = Vrow + (size_t)keyB * S_LEN + lo * 64 + cbB * 8;
    const float* kmrow = km_pen + b * S_LEN + lo * 64 + l;

    unsigned short* const kD0 = &Ks[0][(w * 128) * 8];
    unsigned short* const kD1 = &Ks[0][(w * 128 + 64) * 8];
    unsigned short* const kE0 = &Ks[1][(w * 128) * 8];
    unsigned short* const kE1 = &Ks[1][(w * 128 + 64) * 8];
    unsigned short* const vD0 = &Vs[0][(w * 128) * 8];
    unsigned short* const vD1 = &Vs[0][(w * 128 + 64) * 8];
    unsigned short* const vE0 = &Vs[1][(w * 128) * 8];
    unsigned short* const vE1 = &Vs[1][(w * 128 + 64) * 8];

    const unsigned short* qp0 = Qb + (size_t)(b * S_LEN + qb0 + lr) * D_DIM + h * DH + quad * 8;
    const unsigned short* qp1 = Qb + (size_t)(b * S_LEN + qb1 + lr) * D_DIM + h * DH + quad * 8;
    const short8 qf00 = *(const short8*)(qp0);
    const short8 qf01 = *(const short8*)(qp0 + 32);
    const short8 qf10 = *(const short8*)(qp1);
    const short8 qf11 = *(const short8*)(qp1 + 32);

    f32x4 zero = {0.f, 0.f, 0.f, 0.f};
    f32x4 o0[4], o1[4];
#pragma unroll
    for (int j = 0; j < 4; j++) { o0[j] = zero; o1[j] = zero; }
    float l0 = 0.f, l1 = 0.f;

    const int swz0 = quad ^ (lr & 7);
    const int swz1 = (quad + 4) ^ (lr & 7);
    const int mq = ((quad & 1) << 1) | (quad >> 1);
    const int voff0 = lr * 128 + ((mq ^ (lr & 7)) << 4);
    const char* const Vsb = (const char*)&Vs[0][0];

#define GLDS(src, dst)                                                                  \
    __builtin_amdgcn_global_load_lds((const __attribute__((address_space(1))) void*)(src), \
                                     (__attribute__((address_space(3))) void*)(dst), 16, 0, 0)

    // prologue: stage K(lo)->Ks[0], V(lo)->Vs[0]
    GLDS(kSA, kD0);
    GLDS(kSB, kD1);
    kSA += 64 * D_DIM;
    kSB += 64 * D_DIM;
    GLDS(vSA, vD0);
    GLDS(vSB, vD1);
    vSA += 64;
    vSB += 64;

    for (int kt = lo; kt < hi; ++kt) {
        const int cur = (kt - lo) & 1;
        __syncthreads();  // ONE barrier: drains K(kt),V(kt); prev-tile LDS reads retired
        const float kmsel = *kmrow;
        kmrow += 64;

        if (kt + 1 < hi) {  // prefetch K(kt+1),V(kt+1) into alt buffers
            if (cur) { GLDS(kSA, kD0); GLDS(kSB, kD1); GLDS(vSA, vD0); GLDS(vSB, vD1); }
            else     { GLDS(kSA, kE0); GLDS(kSB, kE1); GLDS(vSA, vE0); GLDS(vSB, vE1); }
            kSA += 64 * D_DIM;
            kSB += 64 * D_DIM;
            vSA += 64;
            vSB += 64;
        }

        const int k0 = kt * 64;
        const bool nm0 = (k0 + 63 <= qb0);  // group0 fully unmasked (wave-uniform)
        const bool nm1 = (k0 + 63 <= qb1);
        const int thr0 = qb0 + lr - k0 - quad * 4;
        const int thr1x = nm1 ? 1000 : (qb1 + lr - k0 - quad * 4);

        // ---- scores both groups; K frags read ONCE; mask applied per nf ----
        float e0[4][4], e1[4][4];
#pragma unroll
        for (int nf = 0; nf < 4; nf++) {
            const int key = nf * 16 + lr;
            const short8 kf0 = *(const short8*)&Ks[cur][(key * 8 + swz0) * 8];
            const short8 kf1 = *(const short8*)&Ks[cur][(key * 8 + swz1) * 8];
            f32x4 z0 = zero, z1 = zero;
            z0 = __builtin_amdgcn_mfma_f32_16x16x32_bf16(kf0, qf00, z0, 0, 0, 0);
            z0 = __builtin_amdgcn_mfma_f32_16x16x32_bf16(kf1, qf01, z0, 0, 0, 0);
            z1 = __builtin_amdgcn_mfma_f32_16x16x32_bf16(kf0, qf10, z1, 0, 0, 0);
            z1 = __builtin_amdgcn_mfma_f32_16x16x32_bf16(kf1, qf11, z1, 0, 0, 0);
            if (nm0) {
#pragma unroll
                for (int r = 0; r < 4; r++) { e0[nf][r] = z0[r]; e1[nf][r] = z1[r]; }
            } else {
#pragma unroll
                for (int r = 0; r < 4; r++) {
                    e0[nf][r] = (nf * 16 + r <= thr0) ? z0[r] : NEGF;
                    e1[nf][r] = (nf * 16 + r <= thr1x) ? z1[r] : NEGF;
                }
            }
        }

        const unsigned long long kb = __ballot(kmsel != 0.0f);
        if (kb) {  // wave-uniform; cold path (key padding mask present)
#pragma unroll
            for (int nf = 0; nf < 4; nf++) {
                const float4 kmq =
                    *(const float4*)(km_pen + (size_t)b * S_LEN + kt * 64 + nf * 16 + quad * 4);
                e0[nf][0] += kmq.x; e0[nf][1] += kmq.y; e0[nf][2] += kmq.z; e0[nf][3] += kmq.w;
                e1[nf][0] += kmq.x; e1[nf][1] += kmq.y; e1[nf][2] += kmq.z; e1[nf][3] += kmq.w;
            }
        }
#pragma unroll
        for (int nf = 0; nf < 4; nf++) {
#pragma unroll
            for (int r = 0; r < 4; r++) {
                e0[nf][r] = __builtin_amdgcn_exp2f(e0[nf][r]);
                e1[nf][r] = __builtin_amdgcn_exp2f(e1[nf][r]);
            }
            l0 += (e0[nf][0] + e0[nf][1]) + (e0[nf][2] + e0[nf][3]);
            l1 += (e1[nf][0] + e1[nf][1]) + (e1[nf][2] + e1[nf][3]);
        }

        // ---- pack P to bf16 in-register (trunc via byte-perm) ----
        unsigned int pw0[8], pw1[8];
#pragma unroll
        for (int ks = 0; ks < 2; ks++)
#pragma unroll
            for (int p = 0; p < 4; p++) {
                const int nf = 2 * ks + (p >> 1);
                const int r0 = (p & 1) * 2;
                pw0[ks * 4 + p] = __builtin_amdgcn_perm(
                    __builtin_bit_cast(unsigned int, e0[nf][r0 + 1]),
                    __builtin_bit_cast(unsigned int, e0[nf][r0]), 0x07060302u);
                pw1[ks * 4 + p] = __builtin_amdgcn_perm(
                    __builtin_bit_cast(unsigned int, e1[nf][r0 + 1]),
                    __builtin_bit_cast(unsigned int, e1[nf][r0]), 0x07060302u);
            }

        // ---- PV: V frags read ONCE, feed both groups ----
        const int vbase = cur << 13;
#pragma unroll
        for (int ks = 0; ks < 2; ks++) {
            const u32x2 a0 = __builtin_amdgcn_permlane16_swap(pw0[ks * 4 + 0], pw0[ks * 4 + 2],
                                                              false, false);
            const u32x2 a1 = __builtin_amdgcn_permlane16_swap(pw0[ks * 4 + 1], pw0[ks * 4 + 3],
                                                              false, false);
            const u32x2 b0 = __builtin_amdgcn_permlane16_swap(pw1[ks * 4 + 0], pw1[ks * 4 + 2],
                                                              false, false);
            const u32x2 b1 = __builtin_amdgcn_permlane16_swap(pw1[ks * 4 + 1], pw1[ks * 4 + 3],
                                                              false, false);
            const u32x4 pq0 = {a0[0], a1[0], a0[1], a1[1]};
            const u32x4 pq1 = {b0[0], b1[0], b0[1], b1[1]};
            const short8 pa0 = __builtin_bit_cast(short8, pq0);
            const short8 pa1 = __builtin_bit_cast(short8, pq1);
            const int off = vbase + (voff0 ^ (ks << 6));
#pragma unroll
            for (int j = 0; j < 4; j++) {
                const short8 vfj = *(const short8*)(Vsb + off + j * 2048);
                o0[j] = __builtin_amdgcn_mfma_f32_16x16x32_bf16(pa0, vfj, o0[j], 0, 0, 0);
                o1[j] = __builtin_amdgcn_mfma_f32_16x16x32_bf16(pa1, vfj, o1[j], 0, 0, 0);
            }
        }
    }
#undef GLDS

    // ---- epilogue: bf16 O-partials + fp32 l-partials (both groups) ----
    unsigned short* oP = (sp == 0) ? oP0 : oP1;
    const int LSTRIDE = BATCH * NHEAD * S_LEN;
    float ls0 = l0, ls1 = l1;
    ls0 += __shfl_xor(ls0, 16);
    ls0 += __shfl_xor(ls0, 32);
    ls1 += __shfl_xor(ls1, 16);
    ls1 += __shfl_xor(ls1, 32);
    if (l < 16) {
        lP[sp * LSTRIDE + (b * NHEAD + h) * S_LEN + qb0 + lr] = ls0;
        lP[sp * LSTRIDE + (b * NHEAD + h) * S_LEN + qb1 + lr] = ls1;
    }
#pragma unroll
    for (int r = 0; r < 4; r++) {
        const int r4 = quad * 4 + r;
#pragma unroll
        for (int j = 0; j < 4; j++) {
            oP[(size_t)(b * S_LEN + qb0 + r4) * D_DIM + h * DH + j * 16 + lr] = f2bf(o0[j][r]);
            oP[(size_t)(b * S_LEN + qb1 + r4) * D_DIM + h * DH + j * 16 + lr] = f2bf(o1[j][r]);
        }
    }
}

// ---------------- residual + layernorm + split-K combine (up to 2 partials) ------------
__global__ __launch_bounds__(256) void ln_kernel(
    const unsigned short* __restrict__ oP0, const unsigned short* __restrict__ oP1,
    const float* __restrict__ lP, const float* __restrict__ qmask,
    const float* __restrict__ queries, const float* __restrict__ gamma,
    const float* __restrict__ beta, float* __restrict__ out) {
    const int row = blockIdx.x;
    const int t = threadIdx.x;
    const int b = row >> 11, q = row & 2047;
    const int ns = ((q >> 7) >= 8) ? 2 : 1;  // 128-row q-tiles, qt>=8 split 2-way
    const int h = t >> 4;
    const int lidx = (b * NHEAD + h) * S_LEN + q;
    const int LSTRIDE = BATCH * NHEAD * S_LEN;

    float ls = lP[lidx];
    const size_t ri = (size_t)row * 256 + t;
    const ushort4 a0 = ((const ushort4*)oP0)[ri];
    float sx = bf2f(a0.x), sy = bf2f(a0.y), sz = bf2f(a0.z), sw = bf2f(a0.w);
    if (ns > 1) {
        ls += lP[LSTRIDE + lidx];
        const ushort4 a1 = ((const ushort4*)oP1)[ri];
        sx += bf2f(a1.x); sy += bf2f(a1.y); sz += bf2f(a1.z); sw += bf2f(a1.w);
    }
    const float qmr = qmask[row];
    const float inv0 = (ls > 0.f) ? qmr / ls : 0.f;

    const float4 qv = ((const float4*)(queries + (size_t)row * D_DIM))[t];
    float4 x;
    x.x = sx * inv0 + qv.x;
    x.y = sy * inv0 + qv.y;
    x.z = sz * inv0 + qv.z;
    x.w = sw * inv0 + qv.w;

    float s = x.x + x.y + x.z + x.w;
    float sq = x.x * x.x + x.y * x.y + x.z * x.z + x.w * x.w;
    for (int o = 1; o < 64; o <<= 1) { s += __shfl_xor(s, o); sq += __shfl_xor(sq, o); }
    __shared__ float rs[4], rq[4];
    const int w = t >> 6;
    if ((t & 63) == 0) { rs[w] = s; rq[w] = sq; }
    __syncthreads();
    s = rs[0] + rs[1] + rs[2] + rs[3];
    sq = rq[0] + rq[1] + rq[2] + rq[3];
    const float mean = s * (1.0f / 1024.0f);
    float var = (sq - s * mean) * (1.0f / 1023.0f);
    var = fmaxf(var, 0.f);
    const float inv = 1.0f / (sqrtf(var) + 1e-8f);
    const float4 g = ((const float4*)gamma)[t];
    const float4 bb = ((const float4*)beta)[t];
    float4 y;
    y.x = g.x * (x.x - mean) * inv + bb.x;
    y.y = g.y * (x.y - mean) * inv + bb.y;
    y.z = g.z * (x.z - mean) * inv + bb.z;
    y.w = g.w * (x.w - mean) * inv + bb.w;
    ((float4*)(out + (size_t)row * D_DIM))[t] = y;
}

extern "C" void kernel_launch(void* const* d_in, const int* in_sizes, int n_in, void* d_out,
                              int out_size, void* d_ws, size_t ws_size, hipStream_t stream) {
    const float* queries = (const float*)d_in[0];
    const float* keys = (const float*)d_in[1];
    const float* values = (const float*)d_in[2];
    const float* Wq = (const float*)d_in[3];
    const float* bq = (const float*)d_in[4];
    const float* Wk = (const float*)d_in[5];
    const float* bk = (const float*)d_in[6];
    const float* Wv = (const float*)d_in[7];
    const float* bv = (const float*)d_in[8];
    const float* gamma = (const float*)d_in[9];
    const float* beta = (const float*)d_in[10];
    float* out = (float*)d_out;
    char* ws = (char*)d_ws;

    const size_t MB = 1048576;
    unsigned short* qin = (unsigned short*)(ws + 0);
    unsigned short* kin = (unsigned short*)(ws + 8 * MB);
    unsigned short* vin = (unsigned short*)(ws + 16 * MB);
    unsigned short* wqb = (unsigned short*)(ws + 24 * MB);
    unsigned short* wkb = (unsigned short*)(ws + 26 * MB);
    unsigned short* wvb = (unsigned short*)(ws + 28 * MB);
    unsigned short* Qb = (unsigned short*)(ws + 30 * MB);
    unsigned short* Kb = (unsigned short*)(ws + 38 * MB);
    unsigned short* Vt = (unsigned short*)(ws + 46 * MB);    // proj z==2 writes transposed
    unsigned short* oP0 = (unsigned short*)(ws + 16 * MB);   // aliases vin (dead after proj)
    unsigned short* oP1 = (unsigned short*)(ws + 56 * MB);
    float* qm = (float*)(ws + 54 * MB);
    float* km = (float*)(ws + 54 * MB + 16384);
    float* lP = (float*)(ws + 54 * MB + 32768);  // 2 x 65536 fp32 = 512KB

    cvt_all_kernel<<<dim3(NROWS + D_DIM, 3), 256, 0, stream>>>(
        queries, keys, values, Wq, Wk, Wv, qin, kin, vin, wqb, wkb, wvb, qm, km);

    proj_kernel<<<768, 256, 0, stream>>>(
        qin, kin, vin, wqb, wkb, wvb, bq, bk, bv, Qb, Kb, Vt);

    attn_kernel<<<dim3(24, NHEAD, BATCH), 256, 0, stream>>>(Qb, Kb, Vt, km, oP0, oP1, lP);

    ln_kernel<<<NROWS, 256, 0, stream>>>(oP0, oP1, lP, qm, queries, gamma, beta, out);
}

// Round 9
// 186.164 us; speedup vs baseline: 1.1354x; 1.0251x over previous
//
#include <hip/hip_runtime.h>

#define S_LEN 2048
#define D_DIM 1024
#define NHEAD 16
#define DH 64
#define BATCH 2
#define NROWS (BATCH * S_LEN)  // 4096
#define QSCALE 0.18033688011112042f  // 0.125 * log2(e): scores land in log2 domain

typedef __attribute__((ext_vector_type(8))) short short8;
typedef __attribute__((ext_vector_type(4))) float f32x4;
typedef __attribute__((ext_vector_type(2))) unsigned int u32x2;
typedef __attribute__((ext_vector_type(4))) unsigned int u32x4;

static __device__ __forceinline__ unsigned short f2bf(float f) {
    unsigned int u = __builtin_bit_cast(unsigned int, f);
    u += 0x7fffu + ((u >> 16) & 1u);
    return (unsigned short)(u >> 16);
}
static __device__ __forceinline__ float bf2f(unsigned short h) {
    unsigned int u = ((unsigned int)h) << 16;
    return __builtin_bit_cast(float, u);
}

// ---------------- fp32 -> bf16 convert (inputs + weights) + fused padding masks --------
__global__ __launch_bounds__(256) void cvt_all_kernel(
    const float* __restrict__ s0, const float* __restrict__ s1, const float* __restrict__ s2,
    const float* __restrict__ w0, const float* __restrict__ w1, const float* __restrict__ w2,
    unsigned short* __restrict__ d0, unsigned short* __restrict__ d1,
    unsigned short* __restrict__ d2, unsigned short* __restrict__ e0,
    unsigned short* __restrict__ e1, unsigned short* __restrict__ e2,
    float* __restrict__ qm, float* __restrict__ km) {
    const int y = blockIdx.y;
    const int row = blockIdx.x;
    const int t = threadIdx.x;
    const float* src;
    unsigned short* dst;
    size_t i;
    if (row < NROWS) {
        src = y == 0 ? s0 : (y == 1 ? s1 : s2);
        dst = y == 0 ? d0 : (y == 1 ? d1 : d2);
        i = (size_t)row * 256 + t;
    } else {
        src = y == 0 ? w0 : (y == 1 ? w1 : w2);
        dst = y == 0 ? e0 : (y == 1 ? e1 : e2);
        i = (size_t)(row - NROWS) * 256 + t;
    }
    float4 v = ((const float4*)src)[i];
    ushort4 o;
    o.x = f2bf(v.x); o.y = f2bf(v.y); o.z = f2bf(v.z); o.w = f2bf(v.w);
    ((ushort4*)dst)[i] = o;
    if (row < NROWS && y < 2) {
        float s = v.x + v.y + v.z + v.w;
        for (int off = 1; off < 64; off <<= 1) s += __shfl_xor(s, off);
        __shared__ float red[4];
        const int w = t >> 6;
        if ((t & 63) == 0) red[w] = s;
        __syncthreads();
        if (t == 0) {
            float tt = red[0] + red[1] + red[2] + red[3];
            if (y == 0)
                qm[row] = (tt != 0.0f) ? 1.0f : 0.0f;
            else
                km[row] = (tt != 0.0f) ? 0.0f : -4294967295.0f;
        }
    }
}

// ---------------- fused QKV projection: O = relu(A @ W^T + b), bf16 MFMA ----------------
// R4 distance-2 pipeline (3 LDS bufs, counted vmcnt(4), GLDS(kt+2) issued at iter kt).
// z==2 (V) transposes the 128x128 output tile THROUGH LDS (XOR-swizzled 16B groups)
// then writes Vt (B,H,dh,S) in 256B contiguous segments (8 read-back passes).
__global__ __launch_bounds__(256) void proj_kernel(
    const unsigned short* __restrict__ A0, const unsigned short* __restrict__ A1,
    const unsigned short* __restrict__ A2, const unsigned short* __restrict__ W0,
    const unsigned short* __restrict__ W1, const unsigned short* __restrict__ W2,
    const float* __restrict__ b0, const float* __restrict__ b1, const float* __restrict__ b2,
    unsigned short* __restrict__ O0, unsigned short* __restrict__ O1,
    unsigned short* __restrict__ O2) {
    const int u = blockIdx.x;
    const int n = u / 96;
    const int rem = u % 96;
    const int m = rem / 3;
    const int z = rem % 3;
    const unsigned short* A;
    const unsigned short* W;
    const float* bias;
    unsigned short* O;
    if (z == 0) { A = A0; W = W0; bias = b0; O = O0; }
    else if (z == 1) { A = A1; W = W1; bias = b1; O = O1; }
    else { A = A2; W = W2; bias = b2; O = O2; }

    // single 48KB pool: Asm = SMEM[0..3*4096), Bsm = SMEM[3*4096..6*4096)
    __shared__ __align__(16) unsigned short SMEM[6 * 128 * 32];
    unsigned short* const Asm = SMEM;
    unsigned short* const Bsm = SMEM + 3 * 4096;

    const int t = threadIdx.x;
    const int w = t >> 6, l = t & 63;
    const int quad = l >> 4, lr = l & 15;
    const int wm = w >> 1, wn = w & 1;
    const int m0 = m * 128, n0 = n * 128;

    f32x4 zero = {0.f, 0.f, 0.f, 0.f};
    f32x4 acc[4][4];
#pragma unroll
    for (int i = 0; i < 4; i++)
#pragma unroll
        for (int j = 0; j < 4; j++) acc[i][j] = zero;

    const int c0 = w * 2, c1 = w * 2 + 1;
    const int ar0 = c0 * 16 + (l >> 2), ar1 = c1 * 16 + (l >> 2);
    const int acs = (((l & 3) ^ ((l >> 3) & 3)) << 3);
    const int sel = ((quad ^ ((lr >> 1) & 3)) << 3);

    const unsigned short* aS0 = A + (size_t)(m0 + ar0) * D_DIM + acs;
    const unsigned short* aS1 = A + (size_t)(m0 + ar1) * D_DIM + acs;
    const unsigned short* bS0 = W + (size_t)(n0 + ar0) * D_DIM + acs;
    const unsigned short* bS1 = W + (size_t)(n0 + ar1) * D_DIM + acs;

#define PGLDS(src, dst)                                                                    \
    __builtin_amdgcn_global_load_lds((const __attribute__((address_space(1))) void*)(src), \
                                     (__attribute__((address_space(3))) void*)(dst), 16, 0, 0)

    const int NT = D_DIM / 32;  // 32
    PGLDS(aS0, &Asm[0 * 4096 + c0 * 512]);
    PGLDS(aS1, &Asm[0 * 4096 + c1 * 512]);
    PGLDS(bS0, &Bsm[0 * 4096 + c0 * 512]);
    PGLDS(bS1, &Bsm[0 * 4096 + c1 * 512]);
    aS0 += 32; aS1 += 32; bS0 += 32; bS1 += 32;
    PGLDS(aS0, &Asm[1 * 4096 + c0 * 512]);
    PGLDS(aS1, &Asm[1 * 4096 + c1 * 512]);
    PGLDS(bS0, &Bsm[1 * 4096 + c0 * 512]);
    PGLDS(bS1, &Bsm[1 * 4096 + c1 * 512]);
    aS0 += 32; aS1 += 32; bS0 += 32; bS1 += 32;

    int cur = 0;
    for (int kt = 0; kt < NT; ++kt) {
        if (kt + 1 < NT)
            asm volatile("s_waitcnt vmcnt(4) lgkmcnt(0)" ::: "memory");
        else
            asm volatile("s_waitcnt vmcnt(0) lgkmcnt(0)" ::: "memory");
        __builtin_amdgcn_s_barrier();
        __builtin_amdgcn_sched_barrier(0);

        if (kt + 2 < NT) {
            int nb = cur + 2;
            if (nb >= 3) nb -= 3;
            PGLDS(aS0, &Asm[nb * 4096 + c0 * 512]);
            PGLDS(aS1, &Asm[nb * 4096 + c1 * 512]);
            PGLDS(bS0, &Bsm[nb * 4096 + c0 * 512]);
            PGLDS(bS1, &Bsm[nb * 4096 + c1 * 512]);
            aS0 += 32; aS1 += 32; bS0 += 32; bS1 += 32;
        }

        short8 af[4], bfr[4];
#pragma unroll
        for (int i = 0; i < 4; i++)
            af[i] = *(const short8*)&Asm[cur * 4096 + (wm * 64 + i * 16 + lr) * 32 + sel];
#pragma unroll
        for (int j = 0; j < 4; j++)
            bfr[j] = *(const short8*)&Bsm[cur * 4096 + (wn * 64 + j * 16 + lr) * 32 + sel];
#pragma unroll
        for (int i = 0; i < 4; i++)
#pragma unroll
            for (int j = 0; j < 4; j++)
                acc[i][j] = __builtin_amdgcn_mfma_f32_16x16x32_bf16(af[i], bfr[j], acc[i][j], 0, 0, 0);

        cur += 1;
        if (cur >= 3) cur = 0;
    }
#undef PGLDS

    if (z == 2) {
        // V epilogue: transpose tile through LDS, write Vt (B,H,dh,S) coalesced.
        __syncthreads();
        char* const T = (char*)SMEM;  // 128 rows (n_local) x 256 B (m_local), XOR-swizzled
        const int bb = m0 >> 11;
        const int sl0 = m0 & 2047;
#pragma unroll
        for (int j = 0; j < 4; j++) {
            const int nl = wn * 64 + j * 16 + lr;
            const float bj = bias[n0 + nl];
            char* const Trow = T + nl * 256;
            const int xr = nl & 7;
#pragma unroll
            for (int i = 0; i < 4; i++) {
                const int mb = wm * 128 + i * 32 + quad * 8;
                const int g = mb >> 4, wo = mb & 15;
                const unsigned int w0 =
                    ((unsigned int)f2bf(fmaxf(acc[i][j][1] + bj, 0.f)) << 16) |
                    f2bf(fmaxf(acc[i][j][0] + bj, 0.f));
                const unsigned int w1 =
                    ((unsigned int)f2bf(fmaxf(acc[i][j][3] + bj, 0.f)) << 16) |
                    f2bf(fmaxf(acc[i][j][2] + bj, 0.f));
                u32x2 pk = {w0, w1};
                *(u32x2*)(Trow + ((g ^ xr) << 4) + wo) = pk;
            }
        }
        __syncthreads();
#pragma unroll
        for (int p = 0; p < 8; p++) {  // 128 rows x 256B = 32KB; 4KB per pass
            const int idx = p * 256 + t;
            const int row = idx >> 4;
            const int cg = idx & 15;
            const short8 vv = *(const short8*)(T + row * 256 + ((cg ^ (row & 7)) << 4));
            const int gn = n0 + row;
            unsigned short* dst =
                O + (size_t)((bb * NHEAD + (gn >> 6)) * DH + (gn & 63)) * S_LEN + sl0 + cg * 8;
            *(short8*)dst = vv;
        }
    } else {
        const float oscale = (z == 0) ? QSCALE : 1.0f;
#pragma unroll
        for (int j = 0; j < 4; j++) {
            const int gn = n0 + wn * 64 + j * 16 + lr;
            const float bj = bias[gn];
#pragma unroll
            for (int i = 0; i < 4; i++) {
                const int gmb = m0 + wm * 64 + i * 16 + quad * 4;
#pragma unroll
                for (int r = 0; r < 4; r++) {
                    float v = fmaxf(acc[i][j][r] + bj, 0.f) * oscale;
                    O[(size_t)(gmb + r) * D_DIM + gn] = f2bf(v);
                }
            }
        }
    }
}

// ---------------- flash attention: R8 QBLK=128 + R9 XCD-grouped dispatch ---------------
// grid (24, H, B) = 768 blocks. R9: flat block id remapped so XCD x (= id%8 under
// round-robin dispatch [T1/m09]) owns bh in {4x..4x+3}: per-XCD KV working set = 4 x
// 512KB = 2MB <= 4MB L2 -> K/V panels stay L2-resident per XCD (were fetched by all 8
// XCDs before). LPT order preserved via pos-major k. Bijective (768 = 96 x 8);
// correctness-neutral if the XCD mapping assumption is wrong.
__global__ __launch_bounds__(256) void attn_kernel(
    const unsigned short* __restrict__ Qb, const unsigned short* __restrict__ Kb,
    const unsigned short* __restrict__ Vt, const float* __restrict__ km_pen,
    unsigned short* __restrict__ oP0, unsigned short* __restrict__ oP1,
    float* __restrict__ lP) {
    __shared__ __align__(16) unsigned short Ks[2][64 * 64];
    __shared__ __align__(16) unsigned short Vs[2][64 * 64];

    const int w = threadIdx.x >> 6, l = threadIdx.x & 63;
    const int quad = l >> 4, lr = l & 15;
    const float NEGF = -4294967295.0f;

    // ---- work assignment: 16 q-tiles (128 rows), T=2qt+2; qt>=8 split 2-way; LPT ----
    static const signed char QT_TAB[24] = {15, 15, 7, 14, 14, 13, 13, 6, 12, 12, 11, 11,
                                           5, 10, 10, 9, 9, 4, 8, 8, 3, 2, 1, 0};
    static const signed char SP_TAB[24] = {0, 1, 0, 0, 1, 0, 1, 0, 0, 1, 0, 1,
                                           0, 0, 1, 0, 1, 0, 0, 1, 0, 0, 0, 0};
    // XCD-grouped remap: id%8 -> xcd; xcd owns bh {4*xcd..4*xcd+3}; pos-major within.
    const int id = blockIdx.x + 24 * blockIdx.y + 384 * blockIdx.z;
    const int k = id >> 3;
    const int bh = ((id & 7) << 2) | (k & 3);
    const int pos = k >> 2;
    const int h = bh & 15, b = bh >> 4;
    const int qt = QT_TAB[pos], sp = SP_TAB[pos];
    const int ns = (qt >= 8) ? 2 : 1;
    const int T = 2 * qt + 2;
    const int lo = sp * T / ns, hi = (sp + 1) * T / ns;

    const int q0 = qt * 128;
    const int qb0 = q0 + w * 16;        // group 0 rows (lower 64)
    const int qb1 = q0 + 64 + w * 16;   // group 1 rows (upper 64)

    const int cA = w * 128 + l;
    const int cB = w * 128 + 64 + l;
    const int keyA = cA >> 3, cbA = (cA & 7) ^ (keyA & 7);
    const int keyB = cB >> 3, cbB = (cB & 7) ^ (keyB & 7);
    const unsigned short* Krow = Kb + (size_t)b * S_LEN * D_DIM + h * DH;
    const unsigned short* Vrow = Vt + (size_t)(b * NHEAD + h) * DH * S_LEN;

    const unsigned short* kSA = Krow + (size_t)(lo * 64 + keyA) * D_DIM + cbA * 8;
    const unsigned short* kSB = Krow + (size_t)(lo * 64 + keyB) * D_DIM + cbB * 8;
    const unsigned short* vSA = Vrow + (size_t)keyA * S_LEN + lo * 64 + cbA * 8;
    const unsigned short* vSB = Vrow + (size_t)keyB * S_LEN + lo * 64 + cbB * 8;
    const float* kmrow = km_pen + b * S_LEN + lo * 64 + l;

    unsigned short* const kD0 = &Ks[0][(w * 128) * 8];
    unsigned short* const kD1 = &Ks[0][(w * 128 + 64) * 8];
    unsigned short* const kE0 = &Ks[1][(w * 128) * 8];
    unsigned short* const kE1 = &Ks[1][(w * 128 + 64) * 8];
    unsigned short* const vD0 = &Vs[0][(w * 128) * 8];
    unsigned short* const vD1 = &Vs[0][(w * 128 + 64) * 8];
    unsigned short* const vE0 = &Vs[1][(w * 128) * 8];
    unsigned short* const vE1 = &Vs[1][(w * 128 + 64) * 8];

    const unsigned short* qp0 = Qb + (size_t)(b * S_LEN + qb0 + lr) * D_DIM + h * DH + quad * 8;
    const unsigned short* qp1 = Qb + (size_t)(b * S_LEN + qb1 + lr) * D_DIM + h * DH + quad * 8;
    const short8 qf00 = *(const short8*)(qp0);
    const short8 qf01 = *(const short8*)(qp0 + 32);
    const short8 qf10 = *(const short8*)(qp1);
    const short8 qf11 = *(const short8*)(qp1 + 32);

    f32x4 zero = {0.f, 0.f, 0.f, 0.f};
    f32x4 o0[4], o1[4];
#pragma unroll
    for (int j = 0; j < 4; j++) { o0[j] = zero; o1[j] = zero; }
    float l0 = 0.f, l1 = 0.f;

    const int swz0 = quad ^ (lr & 7);
    const int swz1 = (quad + 4) ^ (lr & 7);
    const int mq = ((quad & 1) << 1) | (quad >> 1);
    const int voff0 = lr * 128 + ((mq ^ (lr & 7)) << 4);
    const char* const Vsb = (const char*)&Vs[0][0];

#define GLDS(src, dst)                                                                  \
    __builtin_amdgcn_global_load_lds((const __attribute__((address_space(1))) void*)(src), \
                                     (__attribute__((address_space(3))) void*)(dst), 16, 0, 0)

    // prologue: stage K(lo)->Ks[0], V(lo)->Vs[0]
    GLDS(kSA, kD0);
    GLDS(kSB, kD1);
    kSA += 64 * D_DIM;
    kSB += 64 * D_DIM;
    GLDS(vSA, vD0);
    GLDS(vSB, vD1);
    vSA += 64;
    vSB += 64;

    for (int kt = lo; kt < hi; ++kt) {
        const int cur = (kt - lo) & 1;
        __syncthreads();  // ONE barrier: drains K(kt),V(kt); prev-tile LDS reads retired
        const float kmsel = *kmrow;
        kmrow += 64;

        if (kt + 1 < hi) {  // prefetch K(kt+1),V(kt+1) into alt buffers
            if (cur) { GLDS(kSA, kD0); GLDS(kSB, kD1); GLDS(vSA, vD0); GLDS(vSB, vD1); }
            else     { GLDS(kSA, kE0); GLDS(kSB, kE1); GLDS(vSA, vE0); GLDS(vSB, vE1); }
            kSA += 64 * D_DIM;
            kSB += 64 * D_DIM;
            vSA += 64;
            vSB += 64;
        }

        const int k0 = kt * 64;
        const bool nm0 = (k0 + 63 <= qb0);  // group0 fully unmasked (wave-uniform)
        const bool nm1 = (k0 + 63 <= qb1);
        const int thr0 = qb0 + lr - k0 - quad * 4;
        const int thr1x = nm1 ? 1000 : (qb1 + lr - k0 - quad * 4);

        // ---- scores both groups; K frags read ONCE; mask applied per nf ----
        float e0[4][4], e1[4][4];
#pragma unroll
        for (int nf = 0; nf < 4; nf++) {
            const int key = nf * 16 + lr;
            const short8 kf0 = *(const short8*)&Ks[cur][(key * 8 + swz0) * 8];
            const short8 kf1 = *(const short8*)&Ks[cur][(key * 8 + swz1) * 8];
            f32x4 z0 = zero, z1 = zero;
            z0 = __builtin_amdgcn_mfma_f32_16x16x32_bf16(kf0, qf00, z0, 0, 0, 0);
            z0 = __builtin_amdgcn_mfma_f32_16x16x32_bf16(kf1, qf01, z0, 0, 0, 0);
            z1 = __builtin_amdgcn_mfma_f32_16x16x32_bf16(kf0, qf10, z1, 0, 0, 0);
            z1 = __builtin_amdgcn_mfma_f32_16x16x32_bf16(kf1, qf11, z1, 0, 0, 0);
            if (nm0) {
#pragma unroll
                for (int r = 0; r < 4; r++) { e0[nf][r] = z0[r]; e1[nf][r] = z1[r]; }
            } else {
#pragma unroll
                for (int r = 0; r < 4; r++) {
                    e0[nf][r] = (nf * 16 + r <= thr0) ? z0[r] : NEGF;
                    e1[nf][r] = (nf * 16 + r <= thr1x) ? z1[r] : NEGF;
                }
            }
        }

        const unsigned long long kb = __ballot(kmsel != 0.0f);
        if (kb) {  // wave-uniform; cold path (key padding mask present)
#pragma unroll
            for (int nf = 0; nf < 4; nf++) {
                const float4 kmq =
                    *(const float4*)(km_pen + (size_t)b * S_LEN + kt * 64 + nf * 16 + quad * 4);
                e0[nf][0] += kmq.x; e0[nf][1] += kmq.y; e0[nf][2] += kmq.z; e0[nf][3] += kmq.w;
                e1[nf][0] += kmq.x; e1[nf][1] += kmq.y; e1[nf][2] += kmq.z; e1[nf][3] += kmq.w;
            }
        }
#pragma unroll
        for (int nf = 0; nf < 4; nf++) {
#pragma unroll
            for (int r = 0; r < 4; r++) {
                e0[nf][r] = __builtin_amdgcn_exp2f(e0[nf][r]);
                e1[nf][r] = __builtin_amdgcn_exp2f(e1[nf][r]);
            }
            l0 += (e0[nf][0] + e0[nf][1]) + (e0[nf][2] + e0[nf][3]);
            l1 += (e1[nf][0] + e1[nf][1]) + (e1[nf][2] + e1[nf][3]);
        }

        // ---- pack P to bf16 in-register (trunc via byte-perm) ----
        unsigned int pw0[8], pw1[8];
#pragma unroll
        for (int ks = 0; ks < 2; ks++)
#pragma unroll
            for (int p = 0; p < 4; p++) {
                const int nf = 2 * ks + (p >> 1);
                const int r0 = (p & 1) * 2;
                pw0[ks * 4 + p] = __builtin_amdgcn_perm(
                    __builtin_bit_cast(unsigned int, e0[nf][r0 + 1]),
                    __builtin_bit_cast(unsigned int, e0[nf][r0]), 0x07060302u);
                pw1[ks * 4 + p] = __builtin_amdgcn_perm(
                    __builtin_bit_cast(unsigned int, e1[nf][r0 + 1]),
                    __builtin_bit_cast(unsigned int, e1[nf][r0]), 0x07060302u);
            }

        // ---- PV: V frags read ONCE, feed both groups ----
        const int vbase = cur << 13;
#pragma unroll
        for (int ks = 0; ks < 2; ks++) {
            const u32x2 a0 = __builtin_amdgcn_permlane16_swap(pw0[ks * 4 + 0], pw0[ks * 4 + 2],
                                                              false, false);
            const u32x2 a1 = __builtin_amdgcn_permlane16_swap(pw0[ks * 4 + 1], pw0[ks * 4 + 3],
                                                              false, false);
            const u32x2 b0 = __builtin_amdgcn_permlane16_swap(pw1[ks * 4 + 0], pw1[ks * 4 + 2],
                                                              false, false);
            const u32x2 b1 = __builtin_amdgcn_permlane16_swap(pw1[ks * 4 + 1], pw1[ks * 4 + 3],
                                                              false, false);
            const u32x4 pq0 = {a0[0], a1[0], a0[1], a1[1]};
            const u32x4 pq1 = {b0[0], b1[0], b0[1], b1[1]};
            const short8 pa0 = __builtin_bit_cast(short8, pq0);
            const short8 pa1 = __builtin_bit_cast(short8, pq1);
            const int off = vbase + (voff0 ^ (ks << 6));
#pragma unroll
            for (int j = 0; j < 4; j++) {
                const short8 vfj = *(const short8*)(Vsb + off + j * 2048);
                o0[j] = __builtin_amdgcn_mfma_f32_16x16x32_bf16(pa0, vfj, o0[j], 0, 0, 0);
                o1[j] = __builtin_amdgcn_mfma_f32_16x16x32_bf16(pa1, vfj, o1[j], 0, 0, 0);
            }
        }
    }
#undef GLDS

    // ---- epilogue: bf16 O-partials + fp32 l-partials (both groups) ----
    unsigned short* oP = (sp == 0) ? oP0 : oP1;
    const int LSTRIDE = BATCH * NHEAD * S_LEN;
    float ls0 = l0, ls1 = l1;
    ls0 += __shfl_xor(ls0, 16);
    ls0 += __shfl_xor(ls0, 32);
    ls1 += __shfl_xor(ls1, 16);
    ls1 += __shfl_xor(ls1, 32);
    if (l < 16) {
        lP[sp * LSTRIDE + (b * NHEAD + h) * S_LEN + qb0 + lr] = ls0;
        lP[sp * LSTRIDE + (b * NHEAD + h) * S_LEN + qb1 + lr] = ls1;
    }
#pragma unroll
    for (int r = 0; r < 4; r++) {
        const int r4 = quad * 4 + r;
#pragma unroll
        for (int j = 0; j < 4; j++) {
            oP[(size_t)(b * S_LEN + qb0 + r4) * D_DIM + h * DH + j * 16 + lr] = f2bf(o0[j][r]);
            oP[(size_t)(b * S_LEN + qb1 + r4) * D_DIM + h * DH + j * 16 + lr] = f2bf(o1[j][r]);
        }
    }
}

// ---------------- residual + layernorm + split-K combine (up to 2 partials) ------------
__global__ __launch_bounds__(256) void ln_kernel(
    const unsigned short* __restrict__ oP0, const unsigned short* __restrict__ oP1,
    const float* __restrict__ lP, const float* __restrict__ qmask,
    const float* __restrict__ queries, const float* __restrict__ gamma,
    const float* __restrict__ beta, float* __restrict__ out) {
    const int row = blockIdx.x;
    const int t = threadIdx.x;
    const int b = row >> 11, q = row & 2047;
    const int ns = ((q >> 7) >= 8) ? 2 : 1;  // 128-row q-tiles, qt>=8 split 2-way
    const int h = t >> 4;
    const int lidx = (b * NHEAD + h) * S_LEN + q;
    const int LSTRIDE = BATCH * NHEAD * S_LEN;

    float ls = lP[lidx];
    const size_t ri = (size_t)row * 256 + t;
    const ushort4 a0 = ((const ushort4*)oP0)[ri];
    float sx = bf2f(a0.x), sy = bf2f(a0.y), sz = bf2f(a0.z), sw = bf2f(a0.w);
    if (ns > 1) {
        ls += lP[LSTRIDE + lidx];
        const ushort4 a1 = ((const ushort4*)oP1)[ri];
        sx += bf2f(a1.x); sy += bf2f(a1.y); sz += bf2f(a1.z); sw += bf2f(a1.w);
    }
    const float qmr = qmask[row];
    const float inv0 = (ls > 0.f) ? qmr / ls : 0.f;

    const float4 qv = ((const float4*)(queries + (size_t)row * D_DIM))[t];
    float4 x;
    x.x = sx * inv0 + qv.x;
    x.y = sy * inv0 + qv.y;
    x.z = sz * inv0 + qv.z;
    x.w = sw * inv0 + qv.w;

    float s = x.x + x.y + x.z + x.w;
    float sq = x.x * x.x + x.y * x.y + x.z * x.z + x.w * x.w;
    for (int o = 1; o < 64; o <<= 1) { s += __shfl_xor(s, o); sq += __shfl_xor(sq, o); }
    __shared__ float rs[4], rq[4];
    const int w = t >> 6;
    if ((t & 63) == 0) { rs[w] = s; rq[w] = sq; }
    __syncthreads();
    s = rs[0] + rs[1] + rs[2] + rs[3];
    sq = rq[0] + rq[1] + rq[2] + rq[3];
    const float mean = s * (1.0f / 1024.0f);
    float var = (sq - s * mean) * (1.0f / 1023.0f);
    var = fmaxf(var, 0.f);
    const float inv = 1.0f / (sqrtf(var) + 1e-8f);
    const float4 g = ((const float4*)gamma)[t];
    const float4 bb = ((const float4*)beta)[t];
    float4 y;
    y.x = g.x * (x.x - mean) * inv + bb.x;
    y.y = g.y * (x.y - mean) * inv + bb.y;
    y.z = g.z * (x.z - mean) * inv + bb.z;
    y.w = g.w * (x.w - mean) * inv + bb.w;
    ((float4*)(out + (size_t)row * D_DIM))[t] = y;
}

extern "C" void kernel_launch(void* const* d_in, const int* in_sizes, int n_in, void* d_out,
                              int out_size, void* d_ws, size_t ws_size, hipStream_t stream) {
    const float* queries = (const float*)d_in[0];
    const float* keys = (const float*)d_in[1];
    const float* values = (const float*)d_in[2];
    const float* Wq = (const float*)d_in[3];
    const float* bq = (const float*)d_in[4];
    const float* Wk = (const float*)d_in[5];
    const float* bk = (const float*)d_in[6];
    const float* Wv = (const float*)d_in[7];
    const float* bv = (const float*)d_in[8];
    const float* gamma = (const float*)d_in[9];
    const float* beta = (const float*)d_in[10];
    float* out = (float*)d_out;
    char* ws = (char*)d_ws;

    const size_t MB = 1048576;
    unsigned short* qin = (unsigned short*)(ws + 0);
    unsigned short* kin = (unsigned short*)(ws + 8 * MB);
    unsigned short* vin = (unsigned short*)(ws + 16 * MB);
    unsigned short* wqb = (unsigned short*)(ws + 24 * MB);
    unsigned short* wkb = (unsigned short*)(ws + 26 * MB);
    unsigned short* wvb = (unsigned short*)(ws + 28 * MB);
    unsigned short* Qb = (unsigned short*)(ws + 30 * MB);
    unsigned short* Kb = (unsigned short*)(ws + 38 * MB);
    unsigned short* Vt = (unsigned short*)(ws + 46 * MB);    // proj z==2 writes transposed
    unsigned short* oP0 = (unsigned short*)(ws + 16 * MB);   // aliases vin (dead after proj)
    unsigned short* oP1 = (unsigned short*)(ws + 56 * MB);
    float* qm = (float*)(ws + 54 * MB);
    float* km = (float*)(ws + 54 * MB + 16384);
    float* lP = (float*)(ws + 54 * MB + 32768);  // 2 x 65536 fp32 = 512KB

    cvt_all_kernel<<<dim3(NROWS + D_DIM, 3), 256, 0, stream>>>(
        queries, keys, values, Wq, Wk, Wv, qin, kin, vin, wqb, wkb, wvb, qm, km);

    proj_kernel<<<768, 256, 0, stream>>>(
        qin, kin, vin, wqb, wkb, wvb, bq, bk, bv, Qb, Kb, Vt);

    attn_kernel<<<dim3(24, NHEAD, BATCH), 256, 0, stream>>>(Qb, Kb, Vt, km, oP0, oP1, lP);

    ln_kernel<<<NROWS, 256, 0, stream>>>(oP0, oP1, lP, qm, queries, gamma, beta, out);
}

// Round 10
// 185.015 us; speedup vs baseline: 1.1425x; 1.0062x over previous
//
#include <hip/hip_runtime.h>

#define S_LEN 2048
#define D_DIM 1024
#define NHEAD 16
#define DH 64
#define BATCH 2
#define NROWS (BATCH * S_LEN)  // 4096
#define QSCALE 0.18033688011112042f  // 0.125 * log2(e): scores land in log2 domain

typedef __attribute__((ext_vector_type(8))) short short8;
typedef __attribute__((ext_vector_type(4))) float f32x4;
typedef __attribute__((ext_vector_type(2))) unsigned int u32x2;
typedef __attribute__((ext_vector_type(4))) unsigned int u32x4;

static __device__ __forceinline__ unsigned short f2bf(float f) {
    unsigned int u = __builtin_bit_cast(unsigned int, f);
    u += 0x7fffu + ((u >> 16) & 1u);
    return (unsigned short)(u >> 16);
}
static __device__ __forceinline__ float bf2f(unsigned short h) {
    unsigned int u = ((unsigned int)h) << 16;
    return __builtin_bit_cast(float, u);
}

// ---------------- fp32 -> bf16 convert (inputs + weights) + fused padding masks --------
__global__ __launch_bounds__(256) void cvt_all_kernel(
    const float* __restrict__ s0, const float* __restrict__ s1, const float* __restrict__ s2,
    const float* __restrict__ w0, const float* __restrict__ w1, const float* __restrict__ w2,
    unsigned short* __restrict__ d0, unsigned short* __restrict__ d1,
    unsigned short* __restrict__ d2, unsigned short* __restrict__ e0,
    unsigned short* __restrict__ e1, unsigned short* __restrict__ e2,
    float* __restrict__ qm, float* __restrict__ km) {
    const int y = blockIdx.y;
    const int row = blockIdx.x;
    const int t = threadIdx.x;
    const float* src;
    unsigned short* dst;
    size_t i;
    if (row < NROWS) {
        src = y == 0 ? s0 : (y == 1 ? s1 : s2);
        dst = y == 0 ? d0 : (y == 1 ? d1 : d2);
        i = (size_t)row * 256 + t;
    } else {
        src = y == 0 ? w0 : (y == 1 ? w1 : w2);
        dst = y == 0 ? e0 : (y == 1 ? e1 : e2);
        i = (size_t)(row - NROWS) * 256 + t;
    }
    float4 v = ((const float4*)src)[i];
    ushort4 o;
    o.x = f2bf(v.x); o.y = f2bf(v.y); o.z = f2bf(v.z); o.w = f2bf(v.w);
    ((ushort4*)dst)[i] = o;
    if (row < NROWS && y < 2) {
        float s = v.x + v.y + v.z + v.w;
        for (int off = 1; off < 64; off <<= 1) s += __shfl_xor(s, off);
        __shared__ float red[4];
        const int w = t >> 6;
        if ((t & 63) == 0) red[w] = s;
        __syncthreads();
        if (t == 0) {
            float tt = red[0] + red[1] + red[2] + red[3];
            if (y == 0)
                qm[row] = (tt != 0.0f) ? 1.0f : 0.0f;
            else
                km[row] = (tt != 0.0f) ? 0.0f : -4294967295.0f;
        }
    }
}

// ---------------- fused QKV projection: O = relu(A @ W^T + b), bf16 MFMA ----------------
// R4 distance-2 pipeline (3 LDS bufs, counted vmcnt(4), GLDS(kt+2) issued at iter kt).
// z==2 (V) transposes the 128x128 output tile THROUGH LDS (XOR-swizzled 16B groups)
// then writes Vt (B,H,dh,S) in 256B contiguous segments (8 read-back passes).
__global__ __launch_bounds__(256) void proj_kernel(
    const unsigned short* __restrict__ A0, const unsigned short* __restrict__ A1,
    const unsigned short* __restrict__ A2, const unsigned short* __restrict__ W0,
    const unsigned short* __restrict__ W1, const unsigned short* __restrict__ W2,
    const float* __restrict__ b0, const float* __restrict__ b1, const float* __restrict__ b2,
    unsigned short* __restrict__ O0, unsigned short* __restrict__ O1,
    unsigned short* __restrict__ O2) {
    const int u = blockIdx.x;
    const int n = u / 96;
    const int rem = u % 96;
    const int m = rem / 3;
    const int z = rem % 3;
    const unsigned short* A;
    const unsigned short* W;
    const float* bias;
    unsigned short* O;
    if (z == 0) { A = A0; W = W0; bias = b0; O = O0; }
    else if (z == 1) { A = A1; W = W1; bias = b1; O = O1; }
    else { A = A2; W = W2; bias = b2; O = O2; }

    // single 48KB pool: Asm = SMEM[0..3*4096), Bsm = SMEM[3*4096..6*4096)
    __shared__ __align__(16) unsigned short SMEM[6 * 128 * 32];
    unsigned short* const Asm = SMEM;
    unsigned short* const Bsm = SMEM + 3 * 4096;

    const int t = threadIdx.x;
    const int w = t >> 6, l = t & 63;
    const int quad = l >> 4, lr = l & 15;
    const int wm = w >> 1, wn = w & 1;
    const int m0 = m * 128, n0 = n * 128;

    f32x4 zero = {0.f, 0.f, 0.f, 0.f};
    f32x4 acc[4][4];
#pragma unroll
    for (int i = 0; i < 4; i++)
#pragma unroll
        for (int j = 0; j < 4; j++) acc[i][j] = zero;

    const int c0 = w * 2, c1 = w * 2 + 1;
    const int ar0 = c0 * 16 + (l >> 2), ar1 = c1 * 16 + (l >> 2);
    const int acs = (((l & 3) ^ ((l >> 3) & 3)) << 3);
    const int sel = ((quad ^ ((lr >> 1) & 3)) << 3);

    const unsigned short* aS0 = A + (size_t)(m0 + ar0) * D_DIM + acs;
    const unsigned short* aS1 = A + (size_t)(m0 + ar1) * D_DIM + acs;
    const unsigned short* bS0 = W + (size_t)(n0 + ar0) * D_DIM + acs;
    const unsigned short* bS1 = W + (size_t)(n0 + ar1) * D_DIM + acs;

#define PGLDS(src, dst)                                                                    \
    __builtin_amdgcn_global_load_lds((const __attribute__((address_space(1))) void*)(src), \
                                     (__attribute__((address_space(3))) void*)(dst), 16, 0, 0)

    const int NT = D_DIM / 32;  // 32
    PGLDS(aS0, &Asm[0 * 4096 + c0 * 512]);
    PGLDS(aS1, &Asm[0 * 4096 + c1 * 512]);
    PGLDS(bS0, &Bsm[0 * 4096 + c0 * 512]);
    PGLDS(bS1, &Bsm[0 * 4096 + c1 * 512]);
    aS0 += 32; aS1 += 32; bS0 += 32; bS1 += 32;
    PGLDS(aS0, &Asm[1 * 4096 + c0 * 512]);
    PGLDS(aS1, &Asm[1 * 4096 + c1 * 512]);
    PGLDS(bS0, &Bsm[1 * 4096 + c0 * 512]);
    PGLDS(bS1, &Bsm[1 * 4096 + c1 * 512]);
    aS0 += 32; aS1 += 32; bS0 += 32; bS1 += 32;

    int cur = 0;
    for (int kt = 0; kt < NT; ++kt) {
        if (kt + 1 < NT)
            asm volatile("s_waitcnt vmcnt(4) lgkmcnt(0)" ::: "memory");
        else
            asm volatile("s_waitcnt vmcnt(0) lgkmcnt(0)" ::: "memory");
        __builtin_amdgcn_s_barrier();
        __builtin_amdgcn_sched_barrier(0);

        if (kt + 2 < NT) {
            int nb = cur + 2;
            if (nb >= 3) nb -= 3;
            PGLDS(aS0, &Asm[nb * 4096 + c0 * 512]);
            PGLDS(aS1, &Asm[nb * 4096 + c1 * 512]);
            PGLDS(bS0, &Bsm[nb * 4096 + c0 * 512]);
            PGLDS(bS1, &Bsm[nb * 4096 + c1 * 512]);
            aS0 += 32; aS1 += 32; bS0 += 32; bS1 += 32;
        }

        short8 af[4], bfr[4];
#pragma unroll
        for (int i = 0; i < 4; i++)
            af[i] = *(const short8*)&Asm[cur * 4096 + (wm * 64 + i * 16 + lr) * 32 + sel];
#pragma unroll
        for (int j = 0; j < 4; j++)
            bfr[j] = *(const short8*)&Bsm[cur * 4096 + (wn * 64 + j * 16 + lr) * 32 + sel];
#pragma unroll
        for (int i = 0; i < 4; i++)
#pragma unroll
            for (int j = 0; j < 4; j++)
                acc[i][j] = __builtin_amdgcn_mfma_f32_16x16x32_bf16(af[i], bfr[j], acc[i][j], 0, 0, 0);

        cur += 1;
        if (cur >= 3) cur = 0;
    }
#undef PGLDS

    if (z == 2) {
        // V epilogue: transpose tile through LDS, write Vt (B,H,dh,S) coalesced.
        __syncthreads();
        char* const T = (char*)SMEM;  // 128 rows (n_local) x 256 B (m_local), XOR-swizzled
        const int bb = m0 >> 11;
        const int sl0 = m0 & 2047;
#pragma unroll
        for (int j = 0; j < 4; j++) {
            const int nl = wn * 64 + j * 16 + lr;
            const float bj = bias[n0 + nl];
            char* const Trow = T + nl * 256;
            const int xr = nl & 7;
#pragma unroll
            for (int i = 0; i < 4; i++) {
                const int mb = wm * 128 + i * 32 + quad * 8;
                const int g = mb >> 4, wo = mb & 15;
                const unsigned int w0 =
                    ((unsigned int)f2bf(fmaxf(acc[i][j][1] + bj, 0.f)) << 16) |
                    f2bf(fmaxf(acc[i][j][0] + bj, 0.f));
                const unsigned int w1 =
                    ((unsigned int)f2bf(fmaxf(acc[i][j][3] + bj, 0.f)) << 16) |
                    f2bf(fmaxf(acc[i][j][2] + bj, 0.f));
                u32x2 pk = {w0, w1};
                *(u32x2*)(Trow + ((g ^ xr) << 4) + wo) = pk;
            }
        }
        __syncthreads();
#pragma unroll
        for (int p = 0; p < 8; p++) {  // 128 rows x 256B = 32KB; 4KB per pass
            const int idx = p * 256 + t;
            const int row = idx >> 4;
            const int cg = idx & 15;
            const short8 vv = *(const short8*)(T + row * 256 + ((cg ^ (row & 7)) << 4));
            const int gn = n0 + row;
            unsigned short* dst =
                O + (size_t)((bb * NHEAD + (gn >> 6)) * DH + (gn & 63)) * S_LEN + sl0 + cg * 8;
            *(short8*)dst = vv;
        }
    } else {
        const float oscale = (z == 0) ? QSCALE : 1.0f;
#pragma unroll
        for (int j = 0; j < 4; j++) {
            const int gn = n0 + wn * 64 + j * 16 + lr;
            const float bj = bias[gn];
#pragma unroll
            for (int i = 0; i < 4; i++) {
                const int gmb = m0 + wm * 64 + i * 16 + quad * 4;
#pragma unroll
                for (int r = 0; r < 4; r++) {
                    float v = fmaxf(acc[i][j][r] + bj, 0.f) * oscale;
                    O[(size_t)(gmb + r) * D_DIM + gn] = f2bf(v);
                }
            }
        }
    }
}

// ---------------- flash attention: R8 QBLK=128 + R9 XCD dispatch + R10 micro ----------
// R10: (1) T5 setprio(1) around QK and PV MFMA+ds_read clusters (wave role diversity
// between barriers: prefetch-issuing vs MFMA waves). (2) l-sum via ones-MFMA:
// mfma(pa, ONES_bf16, lacc) contracts all keys -> row-sum in every col; replaces
// 32 v_add/tile + 4 epilogue shfls. l now sums exactly the bf16-P used in PV.
__global__ __launch_bounds__(256) void attn_kernel(
    const unsigned short* __restrict__ Qb, const unsigned short* __restrict__ Kb,
    const unsigned short* __restrict__ Vt, const float* __restrict__ km_pen,
    unsigned short* __restrict__ oP0, unsigned short* __restrict__ oP1,
    float* __restrict__ lP) {
    __shared__ __align__(16) unsigned short Ks[2][64 * 64];
    __shared__ __align__(16) unsigned short Vs[2][64 * 64];

    const int w = threadIdx.x >> 6, l = threadIdx.x & 63;
    const int quad = l >> 4, lr = l & 15;
    const float NEGF = -4294967295.0f;

    // ---- work assignment: 16 q-tiles (128 rows), T=2qt+2; qt>=8 split 2-way; LPT ----
    static const signed char QT_TAB[24] = {15, 15, 7, 14, 14, 13, 13, 6, 12, 12, 11, 11,
                                           5, 10, 10, 9, 9, 4, 8, 8, 3, 2, 1, 0};
    static const signed char SP_TAB[24] = {0, 1, 0, 0, 1, 0, 1, 0, 0, 1, 0, 1,
                                           0, 0, 1, 0, 1, 0, 0, 1, 0, 0, 0, 0};
    // XCD-grouped remap: id%8 -> xcd; xcd owns bh {4*xcd..4*xcd+3}; pos-major within.
    const int id = blockIdx.x + 24 * blockIdx.y + 384 * blockIdx.z;
    const int k = id >> 3;
    const int bh = ((id & 7) << 2) | (k & 3);
    const int pos = k >> 2;
    const int h = bh & 15, b = bh >> 4;
    const int qt = QT_TAB[pos], sp = SP_TAB[pos];
    const int ns = (qt >= 8) ? 2 : 1;
    const int T = 2 * qt + 2;
    const int lo = sp * T / ns, hi = (sp + 1) * T / ns;

    const int q0 = qt * 128;
    const int qb0 = q0 + w * 16;        // group 0 rows (lower 64)
    const int qb1 = q0 + 64 + w * 16;   // group 1 rows (upper 64)

    const int cA = w * 128 + l;
    const int cB = w * 128 + 64 + l;
    const int keyA = cA >> 3, cbA = (cA & 7) ^ (keyA & 7);
    const int keyB = cB >> 3, cbB = (cB & 7) ^ (keyB & 7);
    const unsigned short* Krow = Kb + (size_t)b * S_LEN * D_DIM + h * DH;
    const unsigned short* Vrow = Vt + (size_t)(b * NHEAD + h) * DH * S_LEN;

    const unsigned short* kSA = Krow + (size_t)(lo * 64 + keyA) * D_DIM + cbA * 8;
    const unsigned short* kSB = Krow + (size_t)(lo * 64 + keyB) * D_DIM + cbB * 8;
    const unsigned short* vSA = Vrow + (size_t)keyA * S_LEN + lo * 64 + cbA * 8;
    const unsigned short* vSB = Vrow + (size_t)keyB * S_LEN + lo * 64 + cbB * 8;
    const float* kmrow = km_pen + b * S_LEN + lo * 64 + l;

    unsigned short* const kD0 = &Ks[0][(w * 128) * 8];
    unsigned short* const kD1 = &Ks[0][(w * 128 + 64) * 8];
    unsigned short* const kE0 = &Ks[1][(w * 128) * 8];
    unsigned short* const kE1 = &Ks[1][(w * 128 + 64) * 8];
    unsigned short* const vD0 = &Vs[0][(w * 128) * 8];
    unsigned short* const vD1 = &Vs[0][(w * 128 + 64) * 8];
    unsigned short* const vE0 = &Vs[1][(w * 128) * 8];
    unsigned short* const vE1 = &Vs[1][(w * 128 + 64) * 8];

    const unsigned short* qp0 = Qb + (size_t)(b * S_LEN + qb0 + lr) * D_DIM + h * DH + quad * 8;
    const unsigned short* qp1 = Qb + (size_t)(b * S_LEN + qb1 + lr) * D_DIM + h * DH + quad * 8;
    const short8 qf00 = *(const short8*)(qp0);
    const short8 qf01 = *(const short8*)(qp0 + 32);
    const short8 qf10 = *(const short8*)(qp1);
    const short8 qf11 = *(const short8*)(qp1 + 32);

    f32x4 zero = {0.f, 0.f, 0.f, 0.f};
    f32x4 o0[4], o1[4];
#pragma unroll
    for (int j = 0; j < 4; j++) { o0[j] = zero; o1[j] = zero; }
    f32x4 lacc0 = zero, lacc1 = zero;  // row-sum accumulators (ones-MFMA)
    const short s1c = (short)0x3F80;   // bf16 1.0
    const short8 ONES = {s1c, s1c, s1c, s1c, s1c, s1c, s1c, s1c};

    const int swz0 = quad ^ (lr & 7);
    const int swz1 = (quad + 4) ^ (lr & 7);
    const int mq = ((quad & 1) << 1) | (quad >> 1);
    const int voff0 = lr * 128 + ((mq ^ (lr & 7)) << 4);
    const char* const Vsb = (const char*)&Vs[0][0];

#define GLDS(src, dst)                                                                  \
    __builtin_amdgcn_global_load_lds((const __attribute__((address_space(1))) void*)(src), \
                                     (__attribute__((address_space(3))) void*)(dst), 16, 0, 0)

    // prologue: stage K(lo)->Ks[0], V(lo)->Vs[0]
    GLDS(kSA, kD0);
    GLDS(kSB, kD1);
    kSA += 64 * D_DIM;
    kSB += 64 * D_DIM;
    GLDS(vSA, vD0);
    GLDS(vSB, vD1);
    vSA += 64;
    vSB += 64;

    for (int kt = lo; kt < hi; ++kt) {
        const int cur = (kt - lo) & 1;
        __syncthreads();  // ONE barrier: drains K(kt),V(kt); prev-tile LDS reads retired
        const float kmsel = *kmrow;
        kmrow += 64;

        if (kt + 1 < hi) {  // prefetch K(kt+1),V(kt+1) into alt buffers
            if (cur) { GLDS(kSA, kD0); GLDS(kSB, kD1); GLDS(vSA, vD0); GLDS(vSB, vD1); }
            else     { GLDS(kSA, kE0); GLDS(kSB, kE1); GLDS(vSA, vE0); GLDS(vSB, vE1); }
            kSA += 64 * D_DIM;
            kSB += 64 * D_DIM;
            vSA += 64;
            vSB += 64;
        }

        const int k0 = kt * 64;
        const bool nm0 = (k0 + 63 <= qb0);  // group0 fully unmasked (wave-uniform)
        const bool nm1 = (k0 + 63 <= qb1);
        const int thr0 = qb0 + lr - k0 - quad * 4;
        const int thr1x = nm1 ? 1000 : (qb1 + lr - k0 - quad * 4);

        // ---- scores both groups; K frags read ONCE; mask applied per nf ----
        float e0[4][4], e1[4][4];
        __builtin_amdgcn_s_setprio(1);
#pragma unroll
        for (int nf = 0; nf < 4; nf++) {
            const int key = nf * 16 + lr;
            const short8 kf0 = *(const short8*)&Ks[cur][(key * 8 + swz0) * 8];
            const short8 kf1 = *(const short8*)&Ks[cur][(key * 8 + swz1) * 8];
            f32x4 z0 = zero, z1 = zero;
            z0 = __builtin_amdgcn_mfma_f32_16x16x32_bf16(kf0, qf00, z0, 0, 0, 0);
            z0 = __builtin_amdgcn_mfma_f32_16x16x32_bf16(kf1, qf01, z0, 0, 0, 0);
            z1 = __builtin_amdgcn_mfma_f32_16x16x32_bf16(kf0, qf10, z1, 0, 0, 0);
            z1 = __builtin_amdgcn_mfma_f32_16x16x32_bf16(kf1, qf11, z1, 0, 0, 0);
            if (nm0) {
#pragma unroll
                for (int r = 0; r < 4; r++) { e0[nf][r] = z0[r]; e1[nf][r] = z1[r]; }
            } else {
#pragma unroll
                for (int r = 0; r < 4; r++) {
                    e0[nf][r] = (nf * 16 + r <= thr0) ? z0[r] : NEGF;
                    e1[nf][r] = (nf * 16 + r <= thr1x) ? z1[r] : NEGF;
                }
            }
        }
        __builtin_amdgcn_s_setprio(0);

        const unsigned long long kb = __ballot(kmsel != 0.0f);
        if (kb) {  // wave-uniform; cold path (key padding mask present)
#pragma unroll
            for (int nf = 0; nf < 4; nf++) {
                const float4 kmq =
                    *(const float4*)(km_pen + (size_t)b * S_LEN + kt * 64 + nf * 16 + quad * 4);
                e0[nf][0] += kmq.x; e0[nf][1] += kmq.y; e0[nf][2] += kmq.z; e0[nf][3] += kmq.w;
                e1[nf][0] += kmq.x; e1[nf][1] += kmq.y; e1[nf][2] += kmq.z; e1[nf][3] += kmq.w;
            }
        }
#pragma unroll
        for (int nf = 0; nf < 4; nf++)
#pragma unroll
            for (int r = 0; r < 4; r++) {
                e0[nf][r] = __builtin_amdgcn_exp2f(e0[nf][r]);
                e1[nf][r] = __builtin_amdgcn_exp2f(e1[nf][r]);
            }

        // ---- pack P to bf16 in-register (trunc via byte-perm) ----
        unsigned int pw0[8], pw1[8];
#pragma unroll
        for (int ks = 0; ks < 2; ks++)
#pragma unroll
            for (int p = 0; p < 4; p++) {
                const int nf = 2 * ks + (p >> 1);
                const int r0 = (p & 1) * 2;
                pw0[ks * 4 + p] = __builtin_amdgcn_perm(
                    __builtin_bit_cast(unsigned int, e0[nf][r0 + 1]),
                    __builtin_bit_cast(unsigned int, e0[nf][r0]), 0x07060302u);
                pw1[ks * 4 + p] = __builtin_amdgcn_perm(
                    __builtin_bit_cast(unsigned int, e1[nf][r0 + 1]),
                    __builtin_bit_cast(unsigned int, e1[nf][r0]), 0x07060302u);
            }

        // ---- PV: V frags read ONCE, feed both groups; l via ones-MFMA ----
        const int vbase = cur << 13;
        __builtin_amdgcn_s_setprio(1);
#pragma unroll
        for (int ks = 0; ks < 2; ks++) {
            const u32x2 a0 = __builtin_amdgcn_permlane16_swap(pw0[ks * 4 + 0], pw0[ks * 4 + 2],
                                                              false, false);
            const u32x2 a1 = __builtin_amdgcn_permlane16_swap(pw0[ks * 4 + 1], pw0[ks * 4 + 3],
                                                              false, false);
            const u32x2 b0 = __builtin_amdgcn_permlane16_swap(pw1[ks * 4 + 0], pw1[ks * 4 + 2],
                                                              false, false);
            const u32x2 b1 = __builtin_amdgcn_permlane16_swap(pw1[ks * 4 + 1], pw1[ks * 4 + 3],
                                                              false, false);
            const u32x4 pq0 = {a0[0], a1[0], a0[1], a1[1]};
            const u32x4 pq1 = {b0[0], b1[0], b0[1], b1[1]};
            const short8 pa0 = __builtin_bit_cast(short8, pq0);
            const short8 pa1 = __builtin_bit_cast(short8, pq1);
            const int off = vbase + (voff0 ^ (ks << 6));
#pragma unroll
            for (int j = 0; j < 4; j++) {
                const short8 vfj = *(const short8*)(Vsb + off + j * 2048);
                o0[j] = __builtin_amdgcn_mfma_f32_16x16x32_bf16(pa0, vfj, o0[j], 0, 0, 0);
                o1[j] = __builtin_amdgcn_mfma_f32_16x16x32_bf16(pa1, vfj, o1[j], 0, 0, 0);
            }
            lacc0 = __builtin_amdgcn_mfma_f32_16x16x32_bf16(pa0, ONES, lacc0, 0, 0, 0);
            lacc1 = __builtin_amdgcn_mfma_f32_16x16x32_bf16(pa1, ONES, lacc1, 0, 0, 0);
        }
        __builtin_amdgcn_s_setprio(0);
    }
#undef GLDS

    // ---- epilogue: bf16 O-partials + fp32 l-partials (both groups) ----
    // lacc[r] = full row-sum for q-row quad*4+r (replicated in all 16 cols).
    unsigned short* oP = (sp == 0) ? oP0 : oP1;
    const int LSTRIDE = BATCH * NHEAD * S_LEN;
    if (lr == 0) {
#pragma unroll
        for (int r = 0; r < 4; r++) {
            lP[sp * LSTRIDE + (b * NHEAD + h) * S_LEN + qb0 + quad * 4 + r] = lacc0[r];
            lP[sp * LSTRIDE + (b * NHEAD + h) * S_LEN + qb1 + quad * 4 + r] = lacc1[r];
        }
    }
#pragma unroll
    for (int r = 0; r < 4; r++) {
        const int r4 = quad * 4 + r;
#pragma unroll
        for (int j = 0; j < 4; j++) {
            oP[(size_t)(b * S_LEN + qb0 + r4) * D_DIM + h * DH + j * 16 + lr] = f2bf(o0[j][r]);
            oP[(size_t)(b * S_LEN + qb1 + r4) * D_DIM + h * DH + j * 16 + lr] = f2bf(o1[j][r]);
        }
    }
}

// ---------------- residual + layernorm + split-K combine (up to 2 partials) ------------
__global__ __launch_bounds__(256) void ln_kernel(
    const unsigned short* __restrict__ oP0, const unsigned short* __restrict__ oP1,
    const float* __restrict__ lP, const float* __restrict__ qmask,
    const float* __restrict__ queries, const float* __restrict__ gamma,
    const float* __restrict__ beta, float* __restrict__ out) {
    const int row = blockIdx.x;
    const int t = threadIdx.x;
    const int b = row >> 11, q = row & 2047;
    const int ns = ((q >> 7) >= 8) ? 2 : 1;  // 128-row q-tiles, qt>=8 split 2-way
    const int h = t >> 4;
    const int lidx = (b * NHEAD + h) * S_LEN + q;
    const int LSTRIDE = BATCH * NHEAD * S_LEN;

    float ls = lP[lidx];
    const size_t ri = (size_t)row * 256 + t;
    const ushort4 a0 = ((const ushort4*)oP0)[ri];
    float sx = bf2f(a0.x), sy = bf2f(a0.y), sz = bf2f(a0.z), sw = bf2f(a0.w);
    if (ns > 1) {
        ls += lP[LSTRIDE + lidx];
        const ushort4 a1 = ((const ushort4*)oP1)[ri];
        sx += bf2f(a1.x); sy += bf2f(a1.y); sz += bf2f(a1.z); sw += bf2f(a1.w);
    }
    const float qmr = qmask[row];
    const float inv0 = (ls > 0.f) ? qmr / ls : 0.f;

    const float4 qv = ((const float4*)(queries + (size_t)row * D_DIM))[t];
    float4 x;
    x.x = sx * inv0 + qv.x;
    x.y = sy * inv0 + qv.y;
    x.z = sz * inv0 + qv.z;
    x.w = sw * inv0 + qv.w;

    float s = x.x + x.y + x.z + x.w;
    float sq = x.x * x.x + x.y * x.y + x.z * x.z + x.w * x.w;
    for (int o = 1; o < 64; o <<= 1) { s += __shfl_xor(s, o); sq += __shfl_xor(sq, o); }
    __shared__ float rs[4], rq[4];
    const int w = t >> 6;
    if ((t & 63) == 0) { rs[w] = s; rq[w] = sq; }
    __syncthreads();
    s = rs[0] + rs[1] + rs[2] + rs[3];
    sq = rq[0] + rq[1] + rq[2] + rq[3];
    const float mean = s * (1.0f / 1024.0f);
    float var = (sq - s * mean) * (1.0f / 1023.0f);
    var = fmaxf(var, 0.f);
    const float inv = 1.0f / (sqrtf(var) + 1e-8f);
    const float4 g = ((const float4*)gamma)[t];
    const float4 bb = ((const float4*)beta)[t];
    float4 y;
    y.x = g.x * (x.x - mean) * inv + bb.x;
    y.y = g.y * (x.y - mean) * inv + bb.y;
    y.z = g.z * (x.z - mean) * inv + bb.z;
    y.w = g.w * (x.w - mean) * inv + bb.w;
    ((float4*)(out + (size_t)row * D_DIM))[t] = y;
}

extern "C" void kernel_launch(void* const* d_in, const int* in_sizes, int n_in, void* d_out,
                              int out_size, void* d_ws, size_t ws_size, hipStream_t stream) {
    const float* queries = (const float*)d_in[0];
    const float* keys = (const float*)d_in[1];
    const float* values = (const float*)d_in[2];
    const float* Wq = (const float*)d_in[3];
    const float* bq = (const float*)d_in[4];
    const float* Wk = (const float*)d_in[5];
    const float* bk = (const float*)d_in[6];
    const float* Wv = (const float*)d_in[7];
    const float* bv = (const float*)d_in[8];
    const float* gamma = (const float*)d_in[9];
    const float* beta = (const float*)d_in[10];
    float* out = (float*)d_out;
    char* ws = (char*)d_ws;

    const size_t MB = 1048576;
    unsigned short* qin = (unsigned short*)(ws + 0);
    unsigned short* kin = (unsigned short*)(ws + 8 * MB);
    unsigned short* vin = (unsigned short*)(ws + 16 * MB);
    unsigned short* wqb = (unsigned short*)(ws + 24 * MB);
    unsigned short* wkb = (unsigned short*)(ws + 26 * MB);
    unsigned short* wvb = (unsigned short*)(ws + 28 * MB);
    unsigned short* Qb = (unsigned short*)(ws + 30 * MB);
    unsigned short* Kb = (unsigned short*)(ws + 38 * MB);
    unsigned short* Vt = (unsigned short*)(ws + 46 * MB);    // proj z==2 writes transposed
    unsigned short* oP0 = (unsigned short*)(ws + 16 * MB);   // aliases vin (dead after proj)
    unsigned short* oP1 = (unsigned short*)(ws + 56 * MB);
    float* qm = (float*)(ws + 54 * MB);
    float* km = (float*)(ws + 54 * MB + 16384);
    float* lP = (float*)(ws + 54 * MB + 32768);  // 2 x 65536 fp32 = 512KB

    cvt_all_kernel<<<dim3(NROWS + D_DIM, 3), 256, 0, stream>>>(
        queries, keys, values, Wq, Wk, Wv, qin, kin, vin, wqb, wkb, wvb, qm, km);

    proj_kernel<<<768, 256, 0, stream>>>(
        qin, kin, vin, wqb, wkb, wvb, bq, bk, bv, Qb, Kb, Vt);

    attn_kernel<<<dim3(24, NHEAD, BATCH), 256, 0, stream>>>(Qb, Kb, Vt, km, oP0, oP1, lP);

    ln_kernel<<<NROWS, 256, 0, stream>>>(oP0, oP1, lP, qm, queries, gamma, beta, out);
}

// Round 11
// 183.319 us; speedup vs baseline: 1.1531x; 1.0093x over previous
//
#include <hip/hip_runtime.h>

#define S_LEN 2048
#define D_DIM 1024
#define NHEAD 16
#define DH 64
#define BATCH 2
#define NROWS (BATCH * S_LEN)  // 4096
#define QSCALE 0.18033688011112042f  // 0.125 * log2(e): scores land in log2 domain

typedef __attribute__((ext_vector_type(8))) short short8;
typedef __attribute__((ext_vector_type(4))) float f32x4;
typedef __attribute__((ext_vector_type(2))) unsigned int u32x2;
typedef __attribute__((ext_vector_type(4))) unsigned int u32x4;

static __device__ __forceinline__ unsigned short f2bf(float f) {
    unsigned int u = __builtin_bit_cast(unsigned int, f);
    u += 0x7fffu + ((u >> 16) & 1u);
    return (unsigned short)(u >> 16);
}
static __device__ __forceinline__ float bf2f(unsigned short h) {
    unsigned int u = ((unsigned int)h) << 16;
    return __builtin_bit_cast(float, u);
}

// ---------------- fp32 -> bf16 convert (inputs + weights) + fused padding masks --------
__global__ __launch_bounds__(256) void cvt_all_kernel(
    const float* __restrict__ s0, const float* __restrict__ s1, const float* __restrict__ s2,
    const float* __restrict__ w0, const float* __restrict__ w1, const float* __restrict__ w2,
    unsigned short* __restrict__ d0, unsigned short* __restrict__ d1,
    unsigned short* __restrict__ d2, unsigned short* __restrict__ e0,
    unsigned short* __restrict__ e1, unsigned short* __restrict__ e2,
    float* __restrict__ qm, float* __restrict__ km) {
    const int y = blockIdx.y;
    const int row = blockIdx.x;
    const int t = threadIdx.x;
    const float* src;
    unsigned short* dst;
    size_t i;
    if (row < NROWS) {
        src = y == 0 ? s0 : (y == 1 ? s1 : s2);
        dst = y == 0 ? d0 : (y == 1 ? d1 : d2);
        i = (size_t)row * 256 + t;
    } else {
        src = y == 0 ? w0 : (y == 1 ? w1 : w2);
        dst = y == 0 ? e0 : (y == 1 ? e1 : e2);
        i = (size_t)(row - NROWS) * 256 + t;
    }
    float4 v = ((const float4*)src)[i];
    ushort4 o;
    o.x = f2bf(v.x); o.y = f2bf(v.y); o.z = f2bf(v.z); o.w = f2bf(v.w);
    ((ushort4*)dst)[i] = o;
    if (row < NROWS && y < 2) {
        float s = v.x + v.y + v.z + v.w;
        for (int off = 1; off < 64; off <<= 1) s += __shfl_xor(s, off);
        __shared__ float red[4];
        const int w = t >> 6;
        if ((t & 63) == 0) red[w] = s;
        __syncthreads();
        if (t == 0) {
            float tt = red[0] + red[1] + red[2] + red[3];
            if (y == 0)
                qm[row] = (tt != 0.0f) ? 1.0f : 0.0f;
            else
                km[row] = (tt != 0.0f) ? 0.0f : -4294967295.0f;
        }
    }
}

// ---------------- fused QKV projection: O = relu(A @ W^T + b), bf16 MFMA ----------------
// R4 distance-2 pipeline (3 LDS bufs, counted vmcnt(4), GLDS(kt+2) issued at iter kt).
// R11: k-loop unrolled by the buffer period (10 triples + 2-iter tail) so CUR/NB are
// compile-time literals -> ds_read addresses fold to base+imm, prefetch branch and
// cur-wrap VALU disappear (VALUBusy was 47% vs MfmaUtil 23% = VALU-paced).
// z==2 (V) transposes the 128x128 output tile THROUGH LDS (XOR-swizzled 16B groups)
// then writes Vt (B,H,dh,S) in 256B contiguous segments (8 read-back passes).
__global__ __launch_bounds__(256) void proj_kernel(
    const unsigned short* __restrict__ A0, const unsigned short* __restrict__ A1,
    const unsigned short* __restrict__ A2, const unsigned short* __restrict__ W0,
    const unsigned short* __restrict__ W1, const unsigned short* __restrict__ W2,
    const float* __restrict__ b0, const float* __restrict__ b1, const float* __restrict__ b2,
    unsigned short* __restrict__ O0, unsigned short* __restrict__ O1,
    unsigned short* __restrict__ O2) {
    const int u = blockIdx.x;
    const int n = u / 96;
    const int rem = u % 96;
    const int m = rem / 3;
    const int z = rem % 3;
    const unsigned short* A;
    const unsigned short* W;
    const float* bias;
    unsigned short* O;
    if (z == 0) { A = A0; W = W0; bias = b0; O = O0; }
    else if (z == 1) { A = A1; W = W1; bias = b1; O = O1; }
    else { A = A2; W = W2; bias = b2; O = O2; }

    // single 48KB pool: Asm = SMEM[0..3*4096), Bsm = SMEM[3*4096..6*4096)
    __shared__ __align__(16) unsigned short SMEM[6 * 128 * 32];
    unsigned short* const Asm = SMEM;
    unsigned short* const Bsm = SMEM + 3 * 4096;

    const int t = threadIdx.x;
    const int w = t >> 6, l = t & 63;
    const int quad = l >> 4, lr = l & 15;
    const int wm = w >> 1, wn = w & 1;
    const int m0 = m * 128, n0 = n * 128;

    f32x4 zero = {0.f, 0.f, 0.f, 0.f};
    f32x4 acc[4][4];
#pragma unroll
    for (int i = 0; i < 4; i++)
#pragma unroll
        for (int j = 0; j < 4; j++) acc[i][j] = zero;

    const int c0 = w * 2, c1 = w * 2 + 1;
    const int ar0 = c0 * 16 + (l >> 2), ar1 = c1 * 16 + (l >> 2);
    const int acs = (((l & 3) ^ ((l >> 3) & 3)) << 3);
    const int sel = ((quad ^ ((lr >> 1) & 3)) << 3);
    // loop-invariant read offsets (elements); buffer base is a compile-time literal
    const int rowA = (wm * 64 + lr) * 32 + sel;
    const int rowB = (wn * 64 + lr) * 32 + sel;

    const unsigned short* aS0 = A + (size_t)(m0 + ar0) * D_DIM + acs;
    const unsigned short* aS1 = A + (size_t)(m0 + ar1) * D_DIM + acs;
    const unsigned short* bS0 = W + (size_t)(n0 + ar0) * D_DIM + acs;
    const unsigned short* bS1 = W + (size_t)(n0 + ar1) * D_DIM + acs;

#define PGLDS(src, dst)                                                                    \
    __builtin_amdgcn_global_load_lds((const __attribute__((address_space(1))) void*)(src), \
                                     (__attribute__((address_space(3))) void*)(dst), 16, 0, 0)

    // prologue: stage k-tiles 0 and 1 into bufs 0,1 (8 GLDS outstanding)
    PGLDS(aS0, &Asm[0 * 4096 + c0 * 512]);
    PGLDS(aS1, &Asm[0 * 4096 + c1 * 512]);
    PGLDS(bS0, &Bsm[0 * 4096 + c0 * 512]);
    PGLDS(bS1, &Bsm[0 * 4096 + c1 * 512]);
    aS0 += 32; aS1 += 32; bS0 += 32; bS1 += 32;
    PGLDS(aS0, &Asm[1 * 4096 + c0 * 512]);
    PGLDS(aS1, &Asm[1 * 4096 + c1 * 512]);
    PGLDS(bS0, &Bsm[1 * 4096 + c0 * 512]);
    PGLDS(bS1, &Bsm[1 * 4096 + c1 * 512]);
    aS0 += 32; aS1 += 32; bS0 += 32; bS1 += 32;

    // PBODY(CURB, NBB, PREF, LAST): one pipeline step with compile-time buffer indices.
    // Wait semantics identical to R10's dynamic loop: wait(kt) drains exactly tile kt
    // (vmcnt(4) leaves tile kt+1 airborne); LAST uses vmcnt(0).
#define PBODY(CURB, NBB, PREF, LAST)                                                       \
    {                                                                                      \
        if (LAST)                                                                          \
            asm volatile("s_waitcnt vmcnt(0) lgkmcnt(0)" ::: "memory");                    \
        else                                                                               \
            asm volatile("s_waitcnt vmcnt(4) lgkmcnt(0)" ::: "memory");                    \
        __builtin_amdgcn_s_barrier();                                                      \
        __builtin_amdgcn_sched_barrier(0);                                                 \
        if (PREF) {                                                                        \
            PGLDS(aS0, &Asm[(NBB) * 4096 + c0 * 512]);                                     \
            PGLDS(aS1, &Asm[(NBB) * 4096 + c1 * 512]);                                     \
            PGLDS(bS0, &Bsm[(NBB) * 4096 + c0 * 512]);                                     \
            PGLDS(bS1, &Bsm[(NBB) * 4096 + c1 * 512]);                                     \
            aS0 += 32; aS1 += 32; bS0 += 32; bS1 += 32;                                    \
        }                                                                                  \
        short8 af[4], bfr[4];                                                              \
        _Pragma("unroll") for (int i = 0; i < 4; i++)                                      \
            af[i] = *(const short8*)&Asm[(CURB) * 4096 + rowA + i * 512];                  \
        _Pragma("unroll") for (int j = 0; j < 4; j++)                                      \
            bfr[j] = *(const short8*)&Bsm[(CURB) * 4096 + rowB + j * 512];                 \
        _Pragma("unroll") for (int i = 0; i < 4; i++)                                      \
            _Pragma("unroll") for (int j = 0; j < 4; j++)                                  \
                acc[i][j] =                                                                \
                    __builtin_amdgcn_mfma_f32_16x16x32_bf16(af[i], bfr[j], acc[i][j], 0,   \
                                                            0, 0);                         \
    }

    // NT=32 = 10 triples (kt 0..29) + tail kt=30 (cur 0, no prefetch) + kt=31 (cur 1).
#pragma unroll 1
    for (int kt3 = 0; kt3 < 30; kt3 += 3) {
        PBODY(0, 2, true, false);
        PBODY(1, 0, true, false);
        PBODY(2, 1, true, false);
    }
    PBODY(0, 2, false, false);
    PBODY(1, 0, false, true);
#undef PBODY
#undef PGLDS

    if (z == 2) {
        // V epilogue: transpose tile through LDS, write Vt (B,H,dh,S) coalesced.
        __syncthreads();
        char* const T = (char*)SMEM;  // 128 rows (n_local) x 256 B (m_local), XOR-swizzled
        const int bb = m0 >> 11;
        const int sl0 = m0 & 2047;
#pragma unroll
        for (int j = 0; j < 4; j++) {
            const int nl = wn * 64 + j * 16 + lr;
            const float bj = bias[n0 + nl];
            char* const Trow = T + nl * 256;
            const int xr = nl & 7;
#pragma unroll
            for (int i = 0; i < 4; i++) {
                const int mb = wm * 128 + i * 32 + quad * 8;
                const int g = mb >> 4, wo = mb & 15;
                const unsigned int w0 =
                    ((unsigned int)f2bf(fmaxf(acc[i][j][1] + bj, 0.f)) << 16) |
                    f2bf(fmaxf(acc[i][j][0] + bj, 0.f));
                const unsigned int w1 =
                    ((unsigned int)f2bf(fmaxf(acc[i][j][3] + bj, 0.f)) << 16) |
                    f2bf(fmaxf(acc[i][j][2] + bj, 0.f));
                u32x2 pk = {w0, w1};
                *(u32x2*)(Trow + ((g ^ xr) << 4) + wo) = pk;
            }
        }
        __syncthreads();
#pragma unroll
        for (int p = 0; p < 8; p++) {  // 128 rows x 256B = 32KB; 4KB per pass
            const int idx = p * 256 + t;
            const int row = idx >> 4;
            const int cg = idx & 15;
            const short8 vv = *(const short8*)(T + row * 256 + ((cg ^ (row & 7)) << 4));
            const int gn = n0 + row;
            unsigned short* dst =
                O + (size_t)((bb * NHEAD + (gn >> 6)) * DH + (gn & 63)) * S_LEN + sl0 + cg * 8;
            *(short8*)dst = vv;
        }
    } else {
        const float oscale = (z == 0) ? QSCALE : 1.0f;
#pragma unroll
        for (int j = 0; j < 4; j++) {
            const int gn = n0 + wn * 64 + j * 16 + lr;
            const float bj = bias[gn];
#pragma unroll
            for (int i = 0; i < 4; i++) {
                const int gmb = m0 + wm * 64 + i * 16 + quad * 4;
#pragma unroll
                for (int r = 0; r < 4; r++) {
                    float v = fmaxf(acc[i][j][r] + bj, 0.f) * oscale;
                    O[(size_t)(gmb + r) * D_DIM + gn] = f2bf(v);
                }
            }
        }
    }
}

// ---------------- flash attention: R8 QBLK=128 + R9 XCD dispatch + R10 micro ----------
// setprio(1) around QK and PV MFMA+ds_read clusters; l-sum via ones-MFMA.
__global__ __launch_bounds__(256) void attn_kernel(
    const unsigned short* __restrict__ Qb, const unsigned short* __restrict__ Kb,
    const unsigned short* __restrict__ Vt, const float* __restrict__ km_pen,
    unsigned short* __restrict__ oP0, unsigned short* __restrict__ oP1,
    float* __restrict__ lP) {
    __shared__ __align__(16) unsigned short Ks[2][64 * 64];
    __shared__ __align__(16) unsigned short Vs[2][64 * 64];

    const int w = threadIdx.x >> 6, l = threadIdx.x & 63;
    const int quad = l >> 4, lr = l & 15;
    const float NEGF = -4294967295.0f;

    // ---- work assignment: 16 q-tiles (128 rows), T=2qt+2; qt>=8 split 2-way; LPT ----
    static const signed char QT_TAB[24] = {15, 15, 7, 14, 14, 13, 13, 6, 12, 12, 11, 11,
                                           5, 10, 10, 9, 9, 4, 8, 8, 3, 2, 1, 0};
    static const signed char SP_TAB[24] = {0, 1, 0, 0, 1, 0, 1, 0, 0, 1, 0, 1,
                                           0, 0, 1, 0, 1, 0, 0, 1, 0, 0, 0, 0};
    // XCD-grouped remap: id%8 -> xcd; xcd owns bh {4*xcd..4*xcd+3}; pos-major within.
    const int id = blockIdx.x + 24 * blockIdx.y + 384 * blockIdx.z;
    const int k = id >> 3;
    const int bh = ((id & 7) << 2) | (k & 3);
    const int pos = k >> 2;
    const int h = bh & 15, b = bh >> 4;
    const int qt = QT_TAB[pos], sp = SP_TAB[pos];
    const int ns = (qt >= 8) ? 2 : 1;
    const int T = 2 * qt + 2;
    const int lo = sp * T / ns, hi = (sp + 1) * T / ns;

    const int q0 = qt * 128;
    const int qb0 = q0 + w * 16;        // group 0 rows (lower 64)
    const int qb1 = q0 + 64 + w * 16;   // group 1 rows (upper 64)

    const int cA = w * 128 + l;
    const int cB = w * 128 + 64 + l;
    const int keyA = cA >> 3, cbA = (cA & 7) ^ (keyA & 7);
    const int keyB = cB >> 3, cbB = (cB & 7) ^ (keyB & 7);
    const unsigned short* Krow = Kb + (size_t)b * S_LEN * D_DIM + h * DH;
    const unsigned short* Vrow = Vt + (size_t)(b * NHEAD + h) * DH * S_LEN;

    const unsigned short* kSA = Krow + (size_t)(lo * 64 + keyA) * D_DIM + cbA * 8;
    const unsigned short* kSB = Krow + (size_t)(lo * 64 + keyB) * D_DIM + cbB * 8;
    const unsigned short* vSA = Vrow + (size_t)keyA * S_LEN + lo * 64 + cbA * 8;
    const unsigned short* vSB = Vrow + (size_t)keyB * S_LEN + lo * 64 + cbB * 8;
    const float* kmrow = km_pen + b * S_LEN + lo * 64 + l;

    unsigned short* const kD0 = &Ks[0][(w * 128) * 8];
    unsigned short* const kD1 = &Ks[0][(w * 128 + 64) * 8];
    unsigned short* const kE0 = &Ks[1][(w * 128) * 8];
    unsigned short* const kE1 = &Ks[1][(w * 128 + 64) * 8];
    unsigned short* const vD0 = &Vs[0][(w * 128) * 8];
    unsigned short* const vD1 = &Vs[0][(w * 128 + 64) * 8];
    unsigned short* const vE0 = &Vs[1][(w * 128) * 8];
    unsigned short* const vE1 = &Vs[1][(w * 128 + 64) * 8];

    const unsigned short* qp0 = Qb + (size_t)(b * S_LEN + qb0 + lr) * D_DIM + h * DH + quad * 8;
    const unsigned short* qp1 = Qb + (size_t)(b * S_LEN + qb1 + lr) * D_DIM + h * DH + quad * 8;
    const short8 qf00 = *(const short8*)(qp0);
    const short8 qf01 = *(const short8*)(qp0 + 32);
    const short8 qf10 = *(const short8*)(qp1);
    const short8 qf11 = *(const short8*)(qp1 + 32);

    f32x4 zero = {0.f, 0.f, 0.f, 0.f};
    f32x4 o0[4], o1[4];
#pragma unroll
    for (int j = 0; j < 4; j++) { o0[j] = zero; o1[j] = zero; }
    f32x4 lacc0 = zero, lacc1 = zero;  // row-sum accumulators (ones-MFMA)
    const short s1c = (short)0x3F80;   // bf16 1.0
    const short8 ONES = {s1c, s1c, s1c, s1c, s1c, s1c, s1c, s1c};

    const int swz0 = quad ^ (lr & 7);
    const int swz1 = (quad + 4) ^ (lr & 7);
    const int mq = ((quad & 1) << 1) | (quad >> 1);
    const int voff0 = lr * 128 + ((mq ^ (lr & 7)) << 4);
    const char* const Vsb = (const char*)&Vs[0][0];

#define GLDS(src, dst)                                                                  \
    __builtin_amdgcn_global_load_lds((const __attribute__((address_space(1))) void*)(src), \
                                     (__attribute__((address_space(3))) void*)(dst), 16, 0, 0)

    // prologue: stage K(lo)->Ks[0], V(lo)->Vs[0]
    GLDS(kSA, kD0);
    GLDS(kSB, kD1);
    kSA += 64 * D_DIM;
    kSB += 64 * D_DIM;
    GLDS(vSA, vD0);
    GLDS(vSB, vD1);
    vSA += 64;
    vSB += 64;

    for (int kt = lo; kt < hi; ++kt) {
        const int cur = (kt - lo) & 1;
        __syncthreads();  // ONE barrier: drains K(kt),V(kt); prev-tile LDS reads retired
        const float kmsel = *kmrow;
        kmrow += 64;

        if (kt + 1 < hi) {  // prefetch K(kt+1),V(kt+1) into alt buffers
            if (cur) { GLDS(kSA, kD0); GLDS(kSB, kD1); GLDS(vSA, vD0); GLDS(vSB, vD1); }
            else     { GLDS(kSA, kE0); GLDS(kSB, kE1); GLDS(vSA, vE0); GLDS(vSB, vE1); }
            kSA += 64 * D_DIM;
            kSB += 64 * D_DIM;
            vSA += 64;
            vSB += 64;
        }

        const int k0 = kt * 64;
        const bool nm0 = (k0 + 63 <= qb0);  // group0 fully unmasked (wave-uniform)
        const bool nm1 = (k0 + 63 <= qb1);
        const int thr0 = qb0 + lr - k0 - quad * 4;
        const int thr1x = nm1 ? 1000 : (qb1 + lr - k0 - quad * 4);

        // ---- scores both groups; K frags read ONCE; mask applied per nf ----
        float e0[4][4], e1[4][4];
        __builtin_amdgcn_s_setprio(1);
#pragma unroll
        for (int nf = 0; nf < 4; nf++) {
            const int key = nf * 16 + lr;
            const short8 kf0 = *(const short8*)&Ks[cur][(key * 8 + swz0) * 8];
            const short8 kf1 = *(const short8*)&Ks[cur][(key * 8 + swz1) * 8];
            f32x4 z0 = zero, z1 = zero;
            z0 = __builtin_amdgcn_mfma_f32_16x16x32_bf16(kf0, qf00, z0, 0, 0, 0);
            z0 = __builtin_amdgcn_mfma_f32_16x16x32_bf16(kf1, qf01, z0, 0, 0, 0);
            z1 = __builtin_amdgcn_mfma_f32_16x16x32_bf16(kf0, qf10, z1, 0, 0, 0);
            z1 = __builtin_amdgcn_mfma_f32_16x16x32_bf16(kf1, qf11, z1, 0, 0, 0);
            if (nm0) {
#pragma unroll
                for (int r = 0; r < 4; r++) { e0[nf][r] = z0[r]; e1[nf][r] = z1[r]; }
            } else {
#pragma unroll
                for (int r = 0; r < 4; r++) {
                    e0[nf][r] = (nf * 16 + r <= thr0) ? z0[r] : NEGF;
                    e1[nf][r] = (nf * 16 + r <= thr1x) ? z1[r] : NEGF;
                }
            }
        }
        __builtin_amdgcn_s_setprio(0);

        const unsigned long long kb = __ballot(kmsel != 0.0f);
        if (kb) {  // wave-uniform; cold path (key padding mask present)
#pragma unroll
            for (int nf = 0; nf < 4; nf++) {
                const float4 kmq =
                    *(const float4*)(km_pen + (size_t)b * S_LEN + kt * 64 + nf * 16 + quad * 4);
                e0[nf][0] += kmq.x; e0[nf][1] += kmq.y; e0[nf][2] += kmq.z; e0[nf][3] += kmq.w;
                e1[nf][0] += kmq.x; e1[nf][1] += kmq.y; e1[nf][2] += kmq.z; e1[nf][3] += kmq.w;
            }
        }
#pragma unroll
        for (int nf = 0; nf < 4; nf++)
#pragma unroll
            for (int r = 0; r < 4; r++) {
                e0[nf][r] = __builtin_amdgcn_exp2f(e0[nf][r]);
                e1[nf][r] = __builtin_amdgcn_exp2f(e1[nf][r]);
            }

        // ---- pack P to bf16 in-register (trunc via byte-perm) ----
        unsigned int pw0[8], pw1[8];
#pragma unroll
        for (int ks = 0; ks < 2; ks++)
#pragma unroll
            for (int p = 0; p < 4; p++) {
                const int nf = 2 * ks + (p >> 1);
                const int r0 = (p & 1) * 2;
                pw0[ks * 4 + p] = __builtin_amdgcn_perm(
                    __builtin_bit_cast(unsigned int, e0[nf][r0 + 1]),
                    __builtin_bit_cast(unsigned int, e0[nf][r0]), 0x07060302u);
                pw1[ks * 4 + p] = __builtin_amdgcn_perm(
                    __builtin_bit_cast(unsigned int, e1[nf][r0 + 1]),
                    __builtin_bit_cast(unsigned int, e1[nf][r0]), 0x07060302u);
            }

        // ---- PV: V frags read ONCE, feed both groups; l via ones-MFMA ----
        const int vbase = cur << 13;
        __builtin_amdgcn_s_setprio(1);
#pragma unroll
        for (int ks = 0; ks < 2; ks++) {
            const u32x2 a0 = __builtin_amdgcn_permlane16_swap(pw0[ks * 4 + 0], pw0[ks * 4 + 2],
                                                              false, false);
            const u32x2 a1 = __builtin_amdgcn_permlane16_swap(pw0[ks * 4 + 1], pw0[ks * 4 + 3],
                                                              false, false);
            const u32x2 b0 = __builtin_amdgcn_permlane16_swap(pw1[ks * 4 + 0], pw1[ks * 4 + 2],
                                                              false, false);
            const u32x2 b1 = __builtin_amdgcn_permlane16_swap(pw1[ks * 4 + 1], pw1[ks * 4 + 3],
                                                              false, false);
            const u32x4 pq0 = {a0[0], a1[0], a0[1], a1[1]};
            const u32x4 pq1 = {b0[0], b1[0], b0[1], b1[1]};
            const short8 pa0 = __builtin_bit_cast(short8, pq0);
            const short8 pa1 = __builtin_bit_cast(short8, pq1);
            const int off = vbase + (voff0 ^ (ks << 6));
#pragma unroll
            for (int j = 0; j < 4; j++) {
                const short8 vfj = *(const short8*)(Vsb + off + j * 2048);
                o0[j] = __builtin_amdgcn_mfma_f32_16x16x32_bf16(pa0, vfj, o0[j], 0, 0, 0);
                o1[j] = __builtin_amdgcn_mfma_f32_16x16x32_bf16(pa1, vfj, o1[j], 0, 0, 0);
            }
            lacc0 = __builtin_amdgcn_mfma_f32_16x16x32_bf16(pa0, ONES, lacc0, 0, 0, 0);
            lacc1 = __builtin_amdgcn_mfma_f32_16x16x32_bf16(pa1, ONES, lacc1, 0, 0, 0);
        }
        __builtin_amdgcn_s_setprio(0);
    }
#undef GLDS

    // ---- epilogue: bf16 O-partials + fp32 l-partials (both groups) ----
    // lacc[r] = full row-sum for q-row quad*4+r (replicated in all 16 cols).
    unsigned short* oP = (sp == 0) ? oP0 : oP1;
    const int LSTRIDE = BATCH * NHEAD * S_LEN;
    if (lr == 0) {
#pragma unroll
        for (int r = 0; r < 4; r++) {
            lP[sp * LSTRIDE + (b * NHEAD + h) * S_LEN + qb0 + quad * 4 + r] = lacc0[r];
            lP[sp * LSTRIDE + (b * NHEAD + h) * S_LEN + qb1 + quad * 4 + r] = lacc1[r];
        }
    }
#pragma unroll
    for (int r = 0; r < 4; r++) {
        const int r4 = quad * 4 + r;
#pragma unroll
        for (int j = 0; j < 4; j++) {
            oP[(size_t)(b * S_LEN + qb0 + r4) * D_DIM + h * DH + j * 16 + lr] = f2bf(o0[j][r]);
            oP[(size_t)(b * S_LEN + qb1 + r4) * D_DIM + h * DH + j * 16 + lr] = f2bf(o1[j][r]);
        }
    }
}

// ---------------- residual + layernorm + split-K combine (up to 2 partials) ------------
__global__ __launch_bounds__(256) void ln_kernel(
    const unsigned short* __restrict__ oP0, const unsigned short* __restrict__ oP1,
    const float* __restrict__ lP, const float* __restrict__ qmask,
    const float* __restrict__ queries, const float* __restrict__ gamma,
    const float* __restrict__ beta, float* __restrict__ out) {
    const int row = blockIdx.x;
    const int t = threadIdx.x;
    const int b = row >> 11, q = row & 2047;
    const int ns = ((q >> 7) >= 8) ? 2 : 1;  // 128-row q-tiles, qt>=8 split 2-way
    const int h = t >> 4;
    const int lidx = (b * NHEAD + h) * S_LEN + q;
    const int LSTRIDE = BATCH * NHEAD * S_LEN;

    float ls = lP[lidx];
    const size_t ri = (size_t)row * 256 + t;
    const ushort4 a0 = ((const ushort4*)oP0)[ri];
    float sx = bf2f(a0.x), sy = bf2f(a0.y), sz = bf2f(a0.z), sw = bf2f(a0.w);
    if (ns > 1) {
        ls += lP[LSTRIDE + lidx];
        const ushort4 a1 = ((const ushort4*)oP1)[ri];
        sx += bf2f(a1.x); sy += bf2f(a1.y); sz += bf2f(a1.z); sw += bf2f(a1.w);
    }
    const float qmr = qmask[row];
    const float inv0 = (ls > 0.f) ? qmr / ls : 0.f;

    const float4 qv = ((const float4*)(queries + (size_t)row * D_DIM))[t];
    float4 x;
    x.x = sx * inv0 + qv.x;
    x.y = sy * inv0 + qv.y;
    x.z = sz * inv0 + qv.z;
    x.w = sw * inv0 + qv.w;

    float s = x.x + x.y + x.z + x.w;
    float sq = x.x * x.x + x.y * x.y + x.z * x.z + x.w * x.w;
    for (int o = 1; o < 64; o <<= 1) { s += __shfl_xor(s, o); sq += __shfl_xor(sq, o); }
    __shared__ float rs[4], rq[4];
    const int w = t >> 6;
    if ((t & 63) == 0) { rs[w] = s; rq[w] = sq; }
    __syncthreads();
    s = rs[0] + rs[1] + rs[2] + rs[3];
    sq = rq[0] + rq[1] + rq[2] + rq[3];
    const float mean = s * (1.0f / 1024.0f);
    float var = (sq - s * mean) * (1.0f / 1023.0f);
    var = fmaxf(var, 0.f);
    const float inv = 1.0f / (sqrtf(var) + 1e-8f);
    const float4 g = ((const float4*)gamma)[t];
    const float4 bb = ((const float4*)beta)[t];
    float4 y;
    y.x = g.x * (x.x - mean) * inv + bb.x;
    y.y = g.y * (x.y - mean) * inv + bb.y;
    y.z = g.z * (x.z - mean) * inv + bb.z;
    y.w = g.w * (x.w - mean) * inv + bb.w;
    ((float4*)(out + (size_t)row * D_DIM))[t] = y;
}

extern "C" void kernel_launch(void* const* d_in, const int* in_sizes, int n_in, void* d_out,
                              int out_size, void* d_ws, size_t ws_size, hipStream_t stream) {
    const float* queries = (const float*)d_in[0];
    const float* keys = (const float*)d_in[1];
    const float* values = (const float*)d_in[2];
    const float* Wq = (const float*)d_in[3];
    const float* bq = (const float*)d_in[4];
    const float* Wk = (const float*)d_in[5];
    const float* bk = (const float*)d_in[6];
    const float* Wv = (const float*)d_in[7];
    const float* bv = (const float*)d_in[8];
    const float* gamma = (const float*)d_in[9];
    const float* beta = (const float*)d_in[10];
    float* out = (float*)d_out;
    char* ws = (char*)d_ws;

    const size_t MB = 1048576;
    unsigned short* qin = (unsigned short*)(ws + 0);
    unsigned short* kin = (unsigned short*)(ws + 8 * MB);
    unsigned short* vin = (unsigned short*)(ws + 16 * MB);
    unsigned short* wqb = (unsigned short*)(ws + 24 * MB);
    unsigned short* wkb = (unsigned short*)(ws + 26 * MB);
    unsigned short* wvb = (unsigned short*)(ws + 28 * MB);
    unsigned short* Qb = (unsigned short*)(ws + 30 * MB);
    unsigned short* Kb = (unsigned short*)(ws + 38 * MB);
    unsigned short* Vt = (unsigned short*)(ws + 46 * MB);    // proj z==2 writes transposed
    unsigned short* oP0 = (unsigned short*)(ws + 16 * MB);   // aliases vin (dead after proj)
    unsigned short* oP1 = (unsigned short*)(ws + 56 * MB);
    float* qm = (float*)(ws + 54 * MB);
    float* km = (float*)(ws + 54 * MB + 16384);
    float* lP = (float*)(ws + 54 * MB + 32768);  // 2 x 65536 fp32 = 512KB

    cvt_all_kernel<<<dim3(NROWS + D_DIM, 3), 256, 0, stream>>>(
        queries, keys, values, Wq, Wk, Wv, qin, kin, vin, wqb, wkb, wvb, qm, km);

    proj_kernel<<<768, 256, 0, stream>>>(
        qin, kin, vin, wqb, wkb, wvb, bq, bk, bv, Qb, Kb, Vt);

    attn_kernel<<<dim3(24, NHEAD, BATCH), 256, 0, stream>>>(Qb, Kb, Vt, km, oP0, oP1, lP);

    ln_kernel<<<NROWS, 256, 0, stream>>>(oP0, oP1, lP, qm, queries, gamma, beta, out);
}